// Round 2
// baseline (26026.105 us; speedup 1.0000x reference)
//
#include <hip/hip_runtime.h>

// sizes
#define NV 32000
#define NE 512
#define NH 512
#define ND 2048
#define NA 128
#define NB 32
#define NS 49
#define NT 64
#define NBLK 128u

// ws offsets (floats)
#define WS_IMGE   0         // [32*49][512] fp32
#define WS_H      802816    // [32][512]
#define WS_C      819200    // [32][512]
#define WS_CTXE   835584    // [32][512]
#define WS_EMB    851968    // [32][512]
#define WS_X      868352    // [32][512]
#define WS_STATS  884736    // [16 blk][32 b][2]
#define WS_GH     885760    // [32][2048]   (alias: g for prep)
#define WS_BAR    951296    // counter
#define WS_WHIDT  951360    // [512][128]
#define WS_WCTXT  1016896   // [2048][512]  (prep GEMM input)
#define WS_PROJ   1016896   //   alias after k_imge: [32*49][128]
#define WS_H2BF   1217600   //   alias after k_imge: ushort [2048][512]
#define WS_WMIXT  2065472   // [1024][512]
#define WS_WIHT   2589760   // [512][2048]
#define WS_WHHT   3638336   // [512][2048]
#define WS_WBF    4686912   // ushort [32000][512]
#define WS_WIMGT  4686912   //   alias before k_cast: [2048][128]

typedef __attribute__((ext_vector_type(8))) short v8s;
typedef __attribute__((ext_vector_type(4))) float v4f;

__device__ __forceinline__ float fsig(float x) {
    x = fminf(fmaxf(x, -30.f), 30.f);
    return 1.f / (1.f + __expf(-x));
}
__device__ __forceinline__ float ftanh(float x) {
    x = fminf(fmaxf(x, -15.f), 15.f);
    float e = __expf(2.f * x);
    return (e - 1.f) / (e + 1.f);
}
__device__ __forceinline__ unsigned short f2bf(float f) {
    union { float f; unsigned int u; } v; v.f = f;
    unsigned int u = v.u;
    unsigned int r = (u + 0x7FFFu + ((u >> 16) & 1u)) >> 16;
    return (unsigned short)r;
}

// ---------------- one-time kernels ----------------

// out[k*R + r] = in[r*K + k]
__global__ __launch_bounds__(256) void k_transpose(const float* __restrict__ in,
                                                   float* __restrict__ out, int R, int K) {
    __shared__ float tile[32][33];
    int k0 = blockIdx.x * 32, r0 = blockIdx.y * 32;
    int tx = threadIdx.x & 31, ty = threadIdx.x >> 5;
    for (int i = 0; i < 32; i += 8) {
        int r = r0 + ty + i, k = k0 + tx;
        if (r < R && k < K) tile[ty + i][tx] = in[(size_t)r * K + k];
    }
    __syncthreads();
    for (int i = 0; i < 32; i += 8) {
        int k = k0 + ty + i, r = r0 + tx;
        if (k < K && r < R) out[(size_t)k * R + r] = tile[tx][ty + i];
    }
}

__global__ __launch_bounds__(256) void k_cast(const float* __restrict__ in,
                                              unsigned short* __restrict__ out, int n) {
    int i = (blockIdx.x * 256 + threadIdx.x) * 8;
    if (i >= n) return;
    float4 a = *(const float4*)(in + i);
    float4 b = *(const float4*)(in + i + 4);
    uint4 o;
    o.x = (unsigned)f2bf(a.x) | ((unsigned)f2bf(a.y) << 16);
    o.y = (unsigned)f2bf(a.z) | ((unsigned)f2bf(a.w) << 16);
    o.z = (unsigned)f2bf(b.x) | ((unsigned)f2bf(b.y) << 16);
    o.w = (unsigned)f2bf(b.z) | ((unsigned)f2bf(b.w) << 16);
    *(uint4*)(out + i) = o;
}

// imgE[p][e] = sum_d img[p][d] * W_ctx[e][d]  (via wctxT[d][e]); p = b*49+s
__global__ __launch_bounds__(256) void k_imge(const float* __restrict__ img,
        const float* __restrict__ wctxT, float* __restrict__ imgE) {
    int pc = blockIdx.x >> 2, ec = blockIdx.x & 3;
    int tid = threadIdx.x;
    int el = tid & 127, pq = tid >> 7;
    __shared__ float imt[32][128];
    float acc[16] = {};
    int e = ec * 128 + el;
    for (int kt = 0; kt < 16; kt++) {
        __syncthreads();
        for (int idx = tid; idx < 4096; idx += 256) {
            int pi = idx >> 7, d = idx & 127;
            imt[pi][d] = img[(size_t)(pc * 32 + pi) * 2048 + kt * 128 + d];
        }
        __syncthreads();
        for (int d = 0; d < 128; d++) {
            float w = wctxT[(size_t)(kt * 128 + d) * 512 + e];
            #pragma unroll
            for (int i = 0; i < 16; i++) acc[i] += w * imt[pq * 16 + i][d];
        }
    }
    #pragma unroll
    for (int i = 0; i < 16; i++)
        imgE[(size_t)(pc * 32 + pq * 16 + i) * 512 + e] = acc[i];
}

// proj[b][s][a] = sum_d img[b][s][d] * W_img[a][d]   (via W_imgT[d][a])
__global__ __launch_bounds__(128) void k_proj(const float* __restrict__ img,
                                              const float* __restrict__ WimgT,
                                              float* __restrict__ proj) {
    int b = blockIdx.x / 7, sg = blockIdx.x % 7;
    int a = threadIdx.x;
    __shared__ float im[7][128];
    float acc[7] = {0.f,0.f,0.f,0.f,0.f,0.f,0.f};
    for (int dt = 0; dt < 2048; dt += 128) {
        #pragma unroll
        for (int s = 0; s < 7; s++)
            im[s][a] = img[((size_t)(b * 49 + sg * 7 + s)) * 2048 + dt + a];
        __syncthreads();
        for (int d = 0; d < 128; d++) {
            float w = WimgT[(size_t)(dt + d) * 128 + a];
            #pragma unroll
            for (int s = 0; s < 7; s++) acc[s] += im[s][d] * w;
        }
        __syncthreads();
    }
    #pragma unroll
    for (int s = 0; s < 7; s++)
        proj[((size_t)(b * 49 + sg * 7 + s)) * 128 + a] = acc[s];
}

__global__ __launch_bounds__(256) void k_gmean(const float* __restrict__ img,
                                               float* __restrict__ g) {
    int b = blockIdx.x;
    for (int d = threadIdx.x; d < 2048; d += 256) {
        float s = 0.f;
        for (int ss = 0; ss < 49; ss++) s += img[((size_t)(b * 49 + ss)) * 2048 + d];
        g[b * 2048 + d] = s * (1.f / 49.f);
    }
}

__global__ __launch_bounds__(256) void k_h0c0(const float* __restrict__ g,
        const float* __restrict__ Wh0, const float* __restrict__ bh0,
        const float* __restrict__ Wc0, const float* __restrict__ bc0,
        float* __restrict__ h0, float* __restrict__ c0) {
    int b = blockIdx.x >> 1, m = blockIdx.x & 1;
    __shared__ float gs[2048];
    for (int d = threadIdx.x; d < 2048; d += 256) gs[d] = g[b * 2048 + d];
    __syncthreads();
    const float* W = m ? Wc0 : Wh0;
    const float* bb = m ? bc0 : bh0;
    float* out = m ? c0 : h0;
    for (int r = threadIdx.x; r < 512; r += 256) {
        float acc = 0.f;
        const float* wr = W + (size_t)r * 2048;
        for (int d = 0; d < 2048; d += 4) {
            float4 w = *(const float4*)(wr + d);
            acc += w.x * gs[d] + w.y * gs[d + 1] + w.z * gs[d + 2] + w.w * gs[d + 3];
        }
        out[b * 512 + r] = ftanh(acc + bb[r]) * 0.5f;
    }
}

// ---------------- persistent recurrence kernel ----------------

__device__ __forceinline__ void gridbar(unsigned* bar, unsigned target) {
    __syncthreads();
    if (threadIdx.x == 0) {
        __threadfence();
        __hip_atomic_fetch_add(bar, 1u, __ATOMIC_RELAXED, __HIP_MEMORY_SCOPE_AGENT);
        while (__hip_atomic_load(bar, __ATOMIC_RELAXED, __HIP_MEMORY_SCOPE_AGENT) < target)
            __builtin_amdgcn_s_sleep(1);
        __threadfence();
    }
    __syncthreads();
}

union SMem {
    struct { float hs[16][512]; } gh;                                     // 32KB
    struct { float hs[512]; float phh[2][128]; float ph[128];
             float sc[64]; float wsm[64]; } attn;
    struct { float catl[32][256]; } mix;                                  // 32KB
    struct { float xn[16][512]; float gtmp[16][4][16];
             float mu[16]; float rs[16]; } gat;                           // ~36KB
};

__global__ __launch_bounds__(256, 1) void k_persist(
        const int* __restrict__ toks, const float* __restrict__ embed,
        const float* __restrict__ lng, const float* __restrict__ lnb,
        const float* __restrict__ bih, const float* __restrict__ bhh,
        const float* __restrict__ wsc,
        const float* __restrict__ proj, const float* __restrict__ imgE,
        const float* __restrict__ whidT, const float* __restrict__ wmixT,
        const float* __restrict__ wihT, const float* __restrict__ whhT,
        float* __restrict__ H, float* __restrict__ C,
        float* __restrict__ CTXE, float* __restrict__ EMB,
        float* __restrict__ X, float* __restrict__ STATSP,
        float* __restrict__ GH, unsigned* __restrict__ BAR,
        unsigned short* __restrict__ h2bf) {
    __shared__ SMem sm;
    int blk = blockIdx.x, tid = threadIdx.x;
    for (int t = 0; t < NT; t++) {
        // ---- phase 1: gh = h@W_hh^T + biases | per-b attention chain | emb ----
        if (blk < 64) {
            int rc = blk >> 1, bh = blk & 1;
            for (int idx = tid; idx < 8192; idx += 256) {
                int bi = idx >> 9, k = idx & 511;
                sm.gh.hs[bi][k] = H[(bh * 16 + bi) * 512 + k];
            }
            __syncthreads();
            int r = tid & 63, bq = tid >> 6;
            int R = rc * 64 + r;
            float a0 = 0.f, a1 = 0.f, a2 = 0.f, a3 = 0.f;
            const float* wp = whhT + R;
            #pragma unroll 4
            for (int k = 0; k < 512; k++) {
                float w = wp[(size_t)k * 2048];
                a0 += w * sm.gh.hs[bq * 4 + 0][k];
                a1 += w * sm.gh.hs[bq * 4 + 1][k];
                a2 += w * sm.gh.hs[bq * 4 + 2][k];
                a3 += w * sm.gh.hs[bq * 4 + 3][k];
            }
            float bias = bih[R] + bhh[R];
            int b0 = bh * 16 + bq * 4;
            GH[(b0 + 0) * 2048 + R] = a0 + bias;
            GH[(b0 + 1) * 2048 + R] = a1 + bias;
            GH[(b0 + 2) * 2048 + R] = a2 + bias;
            GH[(b0 + 3) * 2048 + R] = a3 + bias;
        } else if (blk < 96) {
            int b = blk - 64;
            for (int k = tid; k < 512; k += 256) sm.attn.hs[k] = H[b * 512 + k];
            __syncthreads();
            {   int a = tid & 127, kh = tid >> 7;
                float p = 0.f;
                for (int k = kh * 256; k < kh * 256 + 256; k++)
                    p += sm.attn.hs[k] * whidT[(size_t)k * 128 + a];
                sm.attn.phh[kh][a] = p;
            }
            __syncthreads();
            if (tid < 128) sm.attn.ph[tid] = sm.attn.phh[0][tid] + sm.attn.phh[1][tid];
            __syncthreads();
            {   int s = tid >> 2, q = tid & 3;
                float p = 0.f;
                if (s < 49) {
                    const float* pr = proj + (size_t)(b * 49 + s) * 128;
                    for (int a = q; a < 128; a += 4)
                        p += ftanh(pr[a] + sm.attn.ph[a]) * wsc[a];
                }
                p += __shfl_xor(p, 1); p += __shfl_xor(p, 2);
                if (s < 49 && q == 0) sm.attn.sc[s] = p;
            }
            __syncthreads();
            if (tid < 64) {
                float v = (tid < 49) ? sm.attn.sc[tid] : -1e30f;
                float m = v;
                for (int o = 32; o > 0; o >>= 1) m = fmaxf(m, __shfl_xor(m, o));
                float e = (tid < 49) ? __expf(v - m) : 0.f;
                float ssum = e;
                for (int o = 32; o > 0; o >>= 1) ssum += __shfl_xor(ssum, o);
                if (tid < 49) sm.attn.wsm[tid] = e / ssum;
            }
            __syncthreads();
            for (int e = tid; e < 512; e += 256) {
                float a = 0.f;
                for (int s = 0; s < 49; s++)
                    a += sm.attn.wsm[s] * imgE[(size_t)(b * 49 + s) * 512 + e];
                CTXE[b * 512 + e] = a;
            }
        } else {
            int b = blk - 96;
            int tok = toks[b * 64 + t];
            for (int k = tid; k < 512; k += 256)
                EMB[b * 512 + k] = (tok == 0) ? 0.f : embed[(size_t)tok * 512 + k];
        }
        gridbar(BAR, NBLK * (unsigned)(3 * t + 1));

        // ---- phase 2: x = relu(cat @ W_mix^T), per-block LN partial stats ----
        if (blk < 16) {
            int e0 = blk * 32;
            int el = tid & 31, bq = tid >> 5;
            float acc[4] = {0.f, 0.f, 0.f, 0.f};
            for (int kt = 0; kt < 4; kt++) {
                __syncthreads();
                for (int idx = tid; idx < 8192; idx += 256) {
                    int bi = idx >> 8, k = idx & 255;
                    int kg = kt * 256 + k;
                    sm.mix.catl[bi][k] = (kg < 512) ? EMB[bi * 512 + kg]
                                                    : CTXE[bi * 512 + (kg - 512)];
                }
                __syncthreads();
                #pragma unroll 4
                for (int k = 0; k < 256; k++) {
                    float w = wmixT[(size_t)(kt * 256 + k) * 512 + e0 + el];
                    #pragma unroll
                    for (int i = 0; i < 4; i++)
                        acc[i] += w * sm.mix.catl[bq * 4 + i][k];
                }
            }
            #pragma unroll
            for (int i = 0; i < 4; i++) {
                float xv = fmaxf(acc[i], 0.f);
                int b = bq * 4 + i;
                X[b * 512 + e0 + el] = xv;
                float p = xv, q = xv * xv;
                for (int o = 16; o > 0; o >>= 1) { p += __shfl_xor(p, o); q += __shfl_xor(q, o); }
                if (el == 0) {
                    STATSP[(blk * 32 + b) * 2 + 0] = p;
                    STATSP[(blk * 32 + b) * 2 + 1] = q;
                }
            }
        }
        gridbar(BAR, NBLK * (unsigned)(3 * t + 2));

        // ---- phase 3: LN+emb, gates = xn@W_ih^T + gh, LSTM cell ----
        if (blk < 64) {
            int jc = blk >> 1, bh = blk & 1;
            if (tid < 16) {
                int b = bh * 16 + tid;
                float s = 0.f, s2 = 0.f;
                for (int p = 0; p < 16; p++) {
                    s  += STATSP[(p * 32 + b) * 2 + 0];
                    s2 += STATSP[(p * 32 + b) * 2 + 1];
                }
                float mu = s * (1.f / 512.f);
                float var = s2 * (1.f / 512.f) - mu * mu;
                sm.gat.mu[tid] = mu;
                sm.gat.rs[tid] = rsqrtf(var + 1e-5f);
            }
            __syncthreads();
            for (int idx = tid; idx < 8192; idx += 256) {
                int bi = idx >> 9, k = idx & 511;
                int b = bh * 16 + bi;
                sm.gat.xn[bi][k] = (X[b * 512 + k] - sm.gat.mu[bi]) * sm.gat.rs[bi]
                                   * lng[k] + lnb[k] + EMB[b * 512 + k];
            }
            __syncthreads();
            int r = tid & 63, bq = tid >> 6;
            int gate = r >> 4, jl = r & 15;
            int R = gate * 512 + jc * 16 + jl;
            float acc[4] = {0.f, 0.f, 0.f, 0.f};
            #pragma unroll 4
            for (int k = 0; k < 512; k++) {
                float w = wihT[(size_t)k * 2048 + R];
                #pragma unroll
                for (int i = 0; i < 4; i++) acc[i] += w * sm.gat.xn[bq * 4 + i][k];
            }
            #pragma unroll
            for (int i = 0; i < 4; i++) {
                int b = bh * 16 + bq * 4 + i;
                sm.gat.gtmp[jl][gate][bq * 4 + i] = acc[i] + GH[b * 2048 + R];
            }
            __syncthreads();
            {
                int jl2 = tid >> 4, bi = tid & 15;
                int b = bh * 16 + bi, j = jc * 16 + jl2;
                float gi = sm.gat.gtmp[jl2][0][bi], gf = sm.gat.gtmp[jl2][1][bi];
                float gg = sm.gat.gtmp[jl2][2][bi], go = sm.gat.gtmp[jl2][3][bi];
                float cold = C[b * 512 + j];
                float c2 = fsig(gf) * cold + fsig(gi) * ftanh(gg);
                float h2 = fsig(go) * ftanh(c2);
                C[b * 512 + j] = c2;
                H[b * 512 + j] = h2;
                h2bf[(size_t)(t * 32 + b) * 512 + j] = f2bf(h2);
            }
        }
        gridbar(BAR, NBLK * (unsigned)(3 * t + 3));
    }
}

// ---------------- deferred head: [2048 x 32000 x 512] bf16 MFMA GEMM ----------------
__global__ __launch_bounds__(256) void k_head(const unsigned short* __restrict__ h2bf,
        const unsigned short* __restrict__ Wbf, float* __restrict__ out) {
    __shared__ unsigned short Al[128][72];
    __shared__ unsigned short Bl[128][72];
    int n0 = blockIdx.x * 128;   // v tile
    int m0 = blockIdx.y * 128;   // (t,b) tile
    int tid = threadIdx.x, lane = tid & 63, wid = tid >> 6;
    int wm = wid >> 1, wn = wid & 1;
    v4f acc[4][4] = {};
    for (int kt = 0; kt < 512; kt += 64) {
        __syncthreads();
        #pragma unroll
        for (int i = 0; i < 4; i++) {
            int idx = i * 256 + tid;
            int row = idx >> 3, c8 = (idx & 7) * 8;
            *(uint4*)&Al[row][c8] = *(const uint4*)&h2bf[(size_t)(m0 + row) * 512 + kt + c8];
            *(uint4*)&Bl[row][c8] = *(const uint4*)&Wbf[(size_t)(n0 + row) * 512 + kt + c8];
        }
        __syncthreads();
        #pragma unroll
        for (int kk = 0; kk < 2; kk++) {
            v8s a[4], bfr[4];
            int ko = kk * 32 + (lane >> 4) * 8;
            #pragma unroll
            for (int mi = 0; mi < 4; mi++)
                a[mi] = *(const v8s*)&Al[wm * 64 + mi * 16 + (lane & 15)][ko];
            #pragma unroll
            for (int ni = 0; ni < 4; ni++)
                bfr[ni] = *(const v8s*)&Bl[wn * 64 + ni * 16 + (lane & 15)][ko];
            #pragma unroll
            for (int mi = 0; mi < 4; mi++)
                #pragma unroll
                for (int ni = 0; ni < 4; ni++)
                    acc[mi][ni] = __builtin_amdgcn_mfma_f32_16x16x32_bf16(a[mi], bfr[ni], acc[mi][ni], 0, 0, 0);
        }
    }
    int col = lane & 15, rbase = (lane >> 4) * 4;
    #pragma unroll
    for (int mi = 0; mi < 4; mi++)
        #pragma unroll
        for (int ni = 0; ni < 4; ni++)
            #pragma unroll
            for (int r = 0; r < 4; r++) {
                int m = m0 + wm * 64 + mi * 16 + rbase + r;
                int v = n0 + wn * 64 + ni * 16 + col;
                int b = m & 31, t = m >> 5;
                out[((size_t)(b * 64 + t)) * 32000 + v] = acc[mi][ni][r];
            }
}

// ---------------- launch ----------------
extern "C" void kernel_launch(void* const* d_in, const int* in_sizes, int n_in,
                              void* d_out, int out_size, void* d_ws, size_t ws_size,
                              hipStream_t stream) {
    const float* img    = (const float*)d_in[0];
    const int*   toks   = (const int*)d_in[1];
    const float* embed  = (const float*)d_in[2];
    const float* W_ctx  = (const float*)d_in[3];
    const float* W_mix  = (const float*)d_in[4];
    const float* ln_g   = (const float*)d_in[5];
    const float* ln_b   = (const float*)d_in[6];
    const float* W_ih   = (const float*)d_in[7];
    const float* W_hh   = (const float*)d_in[8];
    const float* b_ih   = (const float*)d_in[9];
    const float* b_hh   = (const float*)d_in[10];
    const float* W_head = (const float*)d_in[11];
    const float* W_img  = (const float*)d_in[12];
    const float* W_hid  = (const float*)d_in[13];
    const float* w_sc   = (const float*)d_in[14];
    const float* W_h0   = (const float*)d_in[15];
    const float* b_h0   = (const float*)d_in[16];
    const float* W_c0   = (const float*)d_in[17];
    const float* b_c0   = (const float*)d_in[18];

    float* out  = (float*)d_out;
    float* ws   = (float*)d_ws;
    float* imge  = ws + WS_IMGE;
    float* H     = ws + WS_H;
    float* C     = ws + WS_C;
    float* ctxE  = ws + WS_CTXE;
    float* emb   = ws + WS_EMB;
    float* X     = ws + WS_X;
    float* stats = ws + WS_STATS;
    float* gh    = ws + WS_GH;
    float* g     = ws + WS_GH;       // alias (prep only)
    unsigned* bar = (unsigned*)(ws + WS_BAR);
    float* whidT = ws + WS_WHIDT;
    float* wctxT = ws + WS_WCTXT;
    float* proj  = ws + WS_PROJ;     // alias after k_imge
    unsigned short* h2bf = (unsigned short*)(ws + WS_H2BF);  // alias after k_imge
    float* wmixT = ws + WS_WMIXT;
    float* wihT  = ws + WS_WIHT;
    float* whhT  = ws + WS_WHHT;
    unsigned short* Wbf = (unsigned short*)(ws + WS_WBF);
    float* wimgT = ws + WS_WIMGT;    // alias before k_cast

    // prep (order matters for aliases: imge before proj/h2bf use of wctxT region;
    //       proj before cast overwrites wimgT region)
    k_transpose<<<dim3(64, 16), 256, 0, stream>>>(W_ctx, wctxT, 512, 2048);
    k_transpose<<<dim3(16, 4),  256, 0, stream>>>(W_hid, whidT, 128, 512);
    k_transpose<<<dim3(32, 16), 256, 0, stream>>>(W_mix, wmixT, 512, 1024);
    k_transpose<<<dim3(16, 64), 256, 0, stream>>>(W_ih,  wihT,  2048, 512);
    k_transpose<<<dim3(16, 64), 256, 0, stream>>>(W_hh,  whhT,  2048, 512);
    k_transpose<<<dim3(64, 4),  256, 0, stream>>>(W_img, wimgT, 128, 2048);
    k_imge<<<196, 256, 0, stream>>>(img, wctxT, imge);
    k_proj<<<224, 128, 0, stream>>>(img, wimgT, proj);
    k_gmean<<<32, 256, 0, stream>>>(img, g);
    k_h0c0<<<64, 256, 0, stream>>>(g, W_h0, b_h0, W_c0, b_c0, H, C);
    k_cast<<<8000, 256, 0, stream>>>(W_head, Wbf, NV * NH);

    // grid-barrier counter must start at 0 on every replay
    hipMemsetAsync(bar, 0, 256, stream);

    k_persist<<<NBLK, 256, 0, stream>>>(toks, embed, ln_g, ln_b, b_ih, b_hh, w_sc,
                                        proj, imge, whidT, wmixT, wihT, whhT,
                                        H, C, ctxE, emb, X, stats, gh, bar, h2bf);

    k_head<<<dim3(250, 16), 256, 0, stream>>>(h2bf, Wbf, out);
}

// Round 3
// 8210.902 us; speedup vs baseline: 3.1697x; 3.1697x over previous
//
#include <hip/hip_runtime.h>

// sizes
#define NV 32000
#define NT 64
#define NBLK 96u

typedef unsigned long long ull;
typedef __attribute__((ext_vector_type(8))) short v8s;
typedef __attribute__((ext_vector_type(4))) float v4f;

// ws offsets (floats)
#define WS_WBF     0          // ushort [32000][512]
#define WS_IMGBF   8192000    // ushort [1664][2048]
#define WS_WCTXBF  9895936    // ushort [512][2048]
#define WS_WIMGBF  10420224   // ushort [128][2048]
#define WS_WMIXRBF 10551296   // ushort [512][512]
#define WS_IMGE    10682368   // f32 [1664][512]  (imgE, then imgEM overwrites)
#define WS_IMGEBF  11534336   // ushort [1664][512]
#define WS_PROJ    11960320   // f32 [1664][128]
#define WS_G       12173312   // f32 [32][2048]
#define WS_H       12238848   // f32 [32][512]
#define WS_C       12255232   // f32 [32][512]
#define WS_XN      12271616   // f32 [32][512]
#define WS_BAR     12288000   // counter
#define WS_H2BF    12288064   // ushort [2048][512]

__device__ __forceinline__ float fsig(float x) {
    x = fminf(fmaxf(x, -30.f), 30.f);
    return 1.f / (1.f + __expf(-x));
}
__device__ __forceinline__ float ftanh(float x) {
    x = fminf(fmaxf(x, -15.f), 15.f);
    float e = __expf(2.f * x);
    return (e - 1.f) / (e + 1.f);
}
__device__ __forceinline__ unsigned short f2bf(float f) {
    union { float f; unsigned int u; } v; v.f = f;
    unsigned int u = v.u;
    return (unsigned short)((u + 0x7FFFu + ((u >> 16) & 1u)) >> 16);
}

// ---------------- prep kernels ----------------

// out[r][k] (r<Rpad) = (r<R) ? bf16(in[r*ldi + off + k]) : 0    (K mult of 8)
__global__ __launch_bounds__(256) void k_castpad(const float* __restrict__ in,
        unsigned short* __restrict__ out, int R, int Rpad, int K, int ldi, int off) {
    size_t i = ((size_t)blockIdx.x * 256 + threadIdx.x) * 8;
    if (i >= (size_t)Rpad * K) return;
    int r = (int)(i / K), k = (int)(i % K);
    uint4 o = {0, 0, 0, 0};
    if (r < R) {
        const float* p = in + (size_t)r * ldi + off + k;
        float4 a = *(const float4*)(p);
        float4 b = *(const float4*)(p + 4);
        o.x = (unsigned)f2bf(a.x) | ((unsigned)f2bf(a.y) << 16);
        o.y = (unsigned)f2bf(a.z) | ((unsigned)f2bf(a.w) << 16);
        o.z = (unsigned)f2bf(b.x) | ((unsigned)f2bf(b.y) << 16);
        o.w = (unsigned)f2bf(b.z) | ((unsigned)f2bf(b.w) << 16);
    }
    *(uint4*)(out + i) = o;
}

// C[m][n] = sum_k A[m][k]*B[n][k]; M=gridDim.y*128 (padded), N=gridDim.x*128, K mult of 64
__global__ __launch_bounds__(256) void k_gemm(const unsigned short* __restrict__ A,
        const unsigned short* __restrict__ B, float* __restrict__ C, int N, int K) {
    __shared__ unsigned short Al[128][72];
    __shared__ unsigned short Bl[128][72];
    int n0 = blockIdx.x * 128, m0 = blockIdx.y * 128;
    int tid = threadIdx.x, lane = tid & 63, wid = tid >> 6;
    int wm = wid >> 1, wn = wid & 1;
    v4f acc[4][4] = {};
    for (int kt = 0; kt < K; kt += 64) {
        __syncthreads();
        #pragma unroll
        for (int i = 0; i < 4; i++) {
            int idx = i * 256 + tid;
            int row = idx >> 3, c8 = (idx & 7) * 8;
            *(uint4*)&Al[row][c8] = *(const uint4*)&A[(size_t)(m0 + row) * K + kt + c8];
            *(uint4*)&Bl[row][c8] = *(const uint4*)&B[(size_t)(n0 + row) * K + kt + c8];
        }
        __syncthreads();
        #pragma unroll
        for (int kk = 0; kk < 2; kk++) {
            v8s a[4], bfr[4];
            int ko = kk * 32 + (lane >> 4) * 8;
            #pragma unroll
            for (int mi = 0; mi < 4; mi++)
                a[mi] = *(const v8s*)&Al[wm * 64 + mi * 16 + (lane & 15)][ko];
            #pragma unroll
            for (int ni = 0; ni < 4; ni++)
                bfr[ni] = *(const v8s*)&Bl[wn * 64 + ni * 16 + (lane & 15)][ko];
            #pragma unroll
            for (int mi = 0; mi < 4; mi++)
                #pragma unroll
                for (int ni = 0; ni < 4; ni++)
                    acc[mi][ni] = __builtin_amdgcn_mfma_f32_16x16x32_bf16(a[mi], bfr[ni], acc[mi][ni], 0, 0, 0);
        }
    }
    int col = lane & 15, rbase = (lane >> 4) * 4;
    #pragma unroll
    for (int mi = 0; mi < 4; mi++)
        #pragma unroll
        for (int ni = 0; ni < 4; ni++)
            #pragma unroll
            for (int r = 0; r < 4; r++) {
                int m = m0 + wm * 64 + mi * 16 + rbase + r;
                int v = n0 + wn * 64 + ni * 16 + col;
                C[(size_t)m * N + v] = acc[mi][ni][r];
            }
}

__global__ __launch_bounds__(256) void k_gmean(const float* __restrict__ img,
                                               float* __restrict__ g) {
    int b = blockIdx.x;
    for (int d = threadIdx.x; d < 2048; d += 256) {
        float s = 0.f;
        for (int ss = 0; ss < 49; ss++) s += img[((size_t)(b * 49 + ss)) * 2048 + d];
        g[b * 2048 + d] = s * (1.f / 49.f);
    }
}

__global__ __launch_bounds__(256) void k_h0c0(const float* __restrict__ g,
        const float* __restrict__ Wh0, const float* __restrict__ bh0,
        const float* __restrict__ Wc0, const float* __restrict__ bc0,
        float* __restrict__ h0, float* __restrict__ c0) {
    int b = blockIdx.x >> 1, m = blockIdx.x & 1;
    __shared__ float gs[2048];
    for (int d = threadIdx.x; d < 2048; d += 256) gs[d] = g[b * 2048 + d];
    __syncthreads();
    const float* W = m ? Wc0 : Wh0;
    const float* bb = m ? bc0 : bh0;
    float* out = m ? c0 : h0;
    for (int r = threadIdx.x; r < 512; r += 256) {
        float acc = 0.f;
        const float* wr = W + (size_t)r * 2048;
        for (int d = 0; d < 2048; d += 4) {
            float4 w = *(const float4*)(wr + d);
            acc += w.x * gs[d] + w.y * gs[d + 1] + w.z * gs[d + 2] + w.w * gs[d + 3];
        }
        out[b * 512 + r] = ftanh(acc + bb[r]) * 0.5f;
    }
}

// ---------------- persistent recurrence ----------------
// NO fences anywhere: weights stay L2-resident. Cross-block data goes through
// relaxed agent-scope atomics (coherent point). __syncthreads drains vmcnt(0)
// for every wave before thread0 increments the barrier counter.

__device__ __forceinline__ void gridbar(unsigned* bar, unsigned target) {
    __syncthreads();
    if (threadIdx.x == 0) {
        __hip_atomic_fetch_add(bar, 1u, __ATOMIC_RELAXED, __HIP_MEMORY_SCOPE_AGENT);
        while (__hip_atomic_load(bar, __ATOMIC_RELAXED, __HIP_MEMORY_SCOPE_AGENT) < target)
            __builtin_amdgcn_s_sleep(4);
    }
    __syncthreads();
}

union SMem {
    struct {                       // gates role (blocks 0..63)
        float hs[8][512];          // H half     16KB
        float xn[8][512];          // xn half    16KB
        float red[4][1024];        // kh partials 16KB
        float red2[1024];          //            4KB
    } g;
    struct {                       // attention role (blocks 64..95)
        float hb[512];
        float ebs[512];
        float php[8][128];
        float ph[128];
        float scp[64][16];
        float wsm[64];
        float xps[2][512];
        float wred[8][2];
        float bc[2];
    } a;
};

__global__ __launch_bounds__(1024) void k_persist(
        const int* __restrict__ toks, const float* __restrict__ embed,
        const float* __restrict__ lng, const float* __restrict__ lnb,
        const float* __restrict__ bih, const float* __restrict__ bhh,
        const float* __restrict__ wsc, const float* __restrict__ W_hid,
        const float* __restrict__ W_mix, const float* __restrict__ W_hh,
        const float* __restrict__ W_ih, const float* __restrict__ proj,
        const float* __restrict__ imgEM, float* __restrict__ H,
        const float* __restrict__ C0, float* __restrict__ XN,
        unsigned* __restrict__ BAR, unsigned short* __restrict__ h2bf) {
    __shared__ SMem sm;
    int blk = blockIdx.x, tid = threadIdx.x;
    bool is_gates = (blk < 64);

    // gates-role constants
    int jc = blk >> 2, bh = blk & 3, b0 = bh * 8;
    int jl = tid & 31, bi = (tid >> 5) & 7, kh = tid >> 8;
    float c_reg = 0.f;
    if (is_gates && tid < 256)
        c_reg = C0[(b0 + (tid >> 5)) * 512 + jc * 32 + (tid & 31)];
    // attention-role constant
    int b = blk - 64;

    float ghp[4] = {0.f, 0.f, 0.f, 0.f};

    for (int t = 0; t < NT; t++) {
        // ================= phase 1 =================
        if (is_gates) {
            // stage H half via agent atomics
            const ull* Hq = (const ull*)H + (size_t)b0 * 256;
            ull* hq = (ull*)sm.g.hs;
            for (int i = tid; i < 2048; i += 1024)
                hq[i] = __hip_atomic_load((ull*)&Hq[i], __ATOMIC_RELAXED, __HIP_MEMORY_SCOPE_AGENT);
            __syncthreads();
            // gh partial: 4 gates x 128 k
            const float* hrow = sm.g.hs[bi] + kh * 128;
            const float* w0 = W_hh + ((size_t)(0   + jc * 32 + jl)) * 512 + kh * 128;
            const float* w1 = W_hh + ((size_t)(512  + jc * 32 + jl)) * 512 + kh * 128;
            const float* w2 = W_hh + ((size_t)(1024 + jc * 32 + jl)) * 512 + kh * 128;
            const float* w3 = W_hh + ((size_t)(1536 + jc * 32 + jl)) * 512 + kh * 128;
            float a0 = 0.f, a1 = 0.f, a2 = 0.f, a3 = 0.f;
            #pragma unroll 8
            for (int k = 0; k < 128; k += 4) {
                float4 h4 = *(const float4*)(hrow + k);
                float4 q0 = *(const float4*)(w0 + k);
                float4 q1 = *(const float4*)(w1 + k);
                float4 q2 = *(const float4*)(w2 + k);
                float4 q3 = *(const float4*)(w3 + k);
                a0 += q0.x*h4.x + q0.y*h4.y + q0.z*h4.z + q0.w*h4.w;
                a1 += q1.x*h4.x + q1.y*h4.y + q1.z*h4.z + q1.w*h4.w;
                a2 += q2.x*h4.x + q2.y*h4.y + q2.z*h4.z + q2.w*h4.w;
                a3 += q3.x*h4.x + q3.y*h4.y + q3.z*h4.z + q3.w*h4.w;
            }
            if (kh == 0) {
                int Rb = jc * 32 + jl;
                a0 += bih[Rb] + bhh[Rb];
                a1 += bih[512 + Rb] + bhh[512 + Rb];
                a2 += bih[1024 + Rb] + bhh[1024 + Rb];
                a3 += bih[1536 + Rb] + bhh[1536 + Rb];
            }
            ghp[0] = a0; ghp[1] = a1; ghp[2] = a2; ghp[3] = a3;
        } else {
            // ---- attention + mix-lite + LN for batch b ----
            int tok = toks[b * 64 + t];
            if (tid < 256) {
                ull v = __hip_atomic_load((ull*)H + b * 256 + tid, __ATOMIC_RELAXED, __HIP_MEMORY_SCOPE_AGENT);
                ((ull*)sm.a.hb)[tid] = v;
            } else if (tid < 768) {
                int k = tid - 256;
                sm.a.ebs[k] = (tok == 0) ? 0.f : embed[(size_t)tok * 512 + k];
            }
            __syncthreads();
            {   // ph partials
                int a = tid & 127, kq = tid >> 7;
                const float* wr = W_hid + (size_t)a * 512 + kq * 64;
                const float* hp = sm.a.hb + kq * 64;
                float p = 0.f;
                #pragma unroll 8
                for (int k = 0; k < 64; k += 4) {
                    float4 w = *(const float4*)(wr + k);
                    float4 h4 = *(const float4*)(hp + k);
                    p += w.x*h4.x + w.y*h4.y + w.z*h4.z + w.w*h4.w;
                }
                sm.a.php[kq][a] = p;
            }
            __syncthreads();
            if (tid < 128) {
                float p = 0.f;
                #pragma unroll
                for (int kq = 0; kq < 8; kq++) p += sm.a.php[kq][tid];
                sm.a.ph[tid] = p;
            }
            __syncthreads();
            {   // score partials: 64 s-slots x 16 a-groups
                int s = tid >> 4, aq = tid & 15;
                float p = 0.f;
                if (s < 49) {
                    const float* pr = proj + (size_t)(b * 49 + s) * 128 + aq * 8;
                    #pragma unroll
                    for (int a = 0; a < 8; a++)
                        p += ftanh(pr[a] + sm.a.ph[aq * 8 + a]) * wsc[aq * 8 + a];
                }
                sm.a.scp[s][aq] = p;
            }
            __syncthreads();
            if (tid < 64) {   // softmax over 49 (wave 0)
                float v = 0.f;
                #pragma unroll
                for (int q = 0; q < 16; q++) v += sm.a.scp[tid][q];
                if (tid >= 49) v = -1e30f;
                float m = v;
                for (int o = 32; o > 0; o >>= 1) m = fmaxf(m, __shfl_xor(m, o));
                float e = (tid < 49) ? __expf(v - m) : 0.f;
                float su = e;
                for (int o = 32; o > 0; o >>= 1) su += __shfl_xor(su, o);
                sm.a.wsm[tid] = e / su;
            }
            __syncthreads();
            {   // x partial: emb @ WmixL (k half) + sum_s w_s imgEM (s half)
                int e = tid & 511, sh = tid >> 9;
                float xp = 0.f;
                const float* wrow = W_mix + (size_t)e * 1024 + sh * 256;
                const float* ep = sm.a.ebs + sh * 256;
                #pragma unroll 8
                for (int k = 0; k < 256; k += 4) {
                    float4 w = *(const float4*)(wrow + k);
                    float4 e4 = *(const float4*)(ep + k);
                    xp += w.x*e4.x + w.y*e4.y + w.z*e4.z + w.w*e4.w;
                }
                int s0 = sh * 25, s1 = sh ? 49 : 25;
                for (int s = s0; s < s1; s++)
                    xp += sm.a.wsm[s] * imgEM[((size_t)(b * 49 + s)) * 512 + e];
                sm.a.xps[sh][e] = xp;
            }
            __syncthreads();
            if (tid < 512) {   // LN stats
                float x = fmaxf(sm.a.xps[0][tid] + sm.a.xps[1][tid], 0.f);
                float s = x, s2 = x * x;
                for (int o = 32; o > 0; o >>= 1) { s += __shfl_xor(s, o); s2 += __shfl_xor(s2, o); }
                if ((tid & 63) == 0) { sm.a.wred[tid >> 6][0] = s; sm.a.wred[tid >> 6][1] = s2; }
            }
            __syncthreads();
            if (tid == 0) {
                float s = 0.f, s2 = 0.f;
                #pragma unroll
                for (int w = 0; w < 8; w++) { s += sm.a.wred[w][0]; s2 += sm.a.wred[w][1]; }
                float mu = s * (1.f / 512.f);
                float var = s2 * (1.f / 512.f) - mu * mu;
                sm.a.bc[0] = mu; sm.a.bc[1] = rsqrtf(var + 1e-5f);
            }
            __syncthreads();
            if (tid < 512) {
                float x = fmaxf(sm.a.xps[0][tid] + sm.a.xps[1][tid], 0.f);
                float xn = (x - sm.a.bc[0]) * sm.a.bc[1] * lng[tid] + lnb[tid] + sm.a.ebs[tid];
                __hip_atomic_store((unsigned*)&XN[b * 512 + tid], __float_as_uint(xn),
                                   __ATOMIC_RELAXED, __HIP_MEMORY_SCOPE_AGENT);
            }
        }
        gridbar(BAR, NBLK * (unsigned)(2 * t + 1));

        // ================= phase 2 =================
        if (is_gates) {
            const ull* Xq = (const ull*)XN + (size_t)b0 * 256;
            ull* xq = (ull*)sm.g.xn;
            for (int i = tid; i < 2048; i += 1024)
                xq[i] = __hip_atomic_load((ull*)&Xq[i], __ATOMIC_RELAXED, __HIP_MEMORY_SCOPE_AGENT);
            __syncthreads();
            const float* xrow = sm.g.xn[bi] + kh * 128;
            const float* w0 = W_ih + ((size_t)(0    + jc * 32 + jl)) * 512 + kh * 128;
            const float* w1 = W_ih + ((size_t)(512  + jc * 32 + jl)) * 512 + kh * 128;
            const float* w2 = W_ih + ((size_t)(1024 + jc * 32 + jl)) * 512 + kh * 128;
            const float* w3 = W_ih + ((size_t)(1536 + jc * 32 + jl)) * 512 + kh * 128;
            float a0 = ghp[0], a1 = ghp[1], a2 = ghp[2], a3 = ghp[3];
            #pragma unroll 8
            for (int k = 0; k < 128; k += 4) {
                float4 x4 = *(const float4*)(xrow + k);
                float4 q0 = *(const float4*)(w0 + k);
                float4 q1 = *(const float4*)(w1 + k);
                float4 q2 = *(const float4*)(w2 + k);
                float4 q3 = *(const float4*)(w3 + k);
                a0 += q0.x*x4.x + q0.y*x4.y + q0.z*x4.z + q0.w*x4.w;
                a1 += q1.x*x4.x + q1.y*x4.y + q1.z*x4.z + q1.w*x4.w;
                a2 += q2.x*x4.x + q2.y*x4.y + q2.z*x4.z + q2.w*x4.w;
                a3 += q3.x*x4.x + q3.y*x4.y + q3.z*x4.z + q3.w*x4.w;
            }
            int base = bi * 32 + jl;
            sm.g.red[kh][0 * 256 + base] = a0;
            sm.g.red[kh][1 * 256 + base] = a1;
            sm.g.red[kh][2 * 256 + base] = a2;
            sm.g.red[kh][3 * 256 + base] = a3;
            __syncthreads();
            sm.g.red2[tid] = sm.g.red[0][tid] + sm.g.red[1][tid] + sm.g.red[2][tid] + sm.g.red[3][tid];
            __syncthreads();
            if (tid < 256) {
                float gi_ = sm.g.red2[tid];
                float gf_ = sm.g.red2[256 + tid];
                float gg_ = sm.g.red2[512 + tid];
                float go_ = sm.g.red2[768 + tid];
                float c2 = fsig(gf_) * c_reg + fsig(gi_) * ftanh(gg_);
                float h2 = fsig(go_) * ftanh(c2);
                c_reg = c2;
                int bb2 = b0 + (tid >> 5), j = jc * 32 + (tid & 31);
                __hip_atomic_store((unsigned*)&H[bb2 * 512 + j], __float_as_uint(h2),
                                   __ATOMIC_RELAXED, __HIP_MEMORY_SCOPE_AGENT);
                h2bf[(size_t)(t * 32 + bb2) * 512 + j] = f2bf(h2);
            }
        }
        gridbar(BAR, NBLK * (unsigned)(2 * t + 2));
    }
}

// ---------------- deferred head GEMM ----------------
__global__ __launch_bounds__(256) void k_head(const unsigned short* __restrict__ h2bf,
        const unsigned short* __restrict__ Wbf, float* __restrict__ out) {
    __shared__ unsigned short Al[128][72];
    __shared__ unsigned short Bl[128][72];
    int n0 = blockIdx.x * 128, m0 = blockIdx.y * 128;
    int tid = threadIdx.x, lane = tid & 63, wid = tid >> 6;
    int wm = wid >> 1, wn = wid & 1;
    v4f acc[4][4] = {};
    for (int kt = 0; kt < 512; kt += 64) {
        __syncthreads();
        #pragma unroll
        for (int i = 0; i < 4; i++) {
            int idx = i * 256 + tid;
            int row = idx >> 3, c8 = (idx & 7) * 8;
            *(uint4*)&Al[row][c8] = *(const uint4*)&h2bf[(size_t)(m0 + row) * 512 + kt + c8];
            *(uint4*)&Bl[row][c8] = *(const uint4*)&Wbf[(size_t)(n0 + row) * 512 + kt + c8];
        }
        __syncthreads();
        #pragma unroll
        for (int kk = 0; kk < 2; kk++) {
            v8s a[4], bfr[4];
            int ko = kk * 32 + (lane >> 4) * 8;
            #pragma unroll
            for (int mi = 0; mi < 4; mi++)
                a[mi] = *(const v8s*)&Al[wm * 64 + mi * 16 + (lane & 15)][ko];
            #pragma unroll
            for (int ni = 0; ni < 4; ni++)
                bfr[ni] = *(const v8s*)&Bl[wn * 64 + ni * 16 + (lane & 15)][ko];
            #pragma unroll
            for (int mi = 0; mi < 4; mi++)
                #pragma unroll
                for (int ni = 0; ni < 4; ni++)
                    acc[mi][ni] = __builtin_amdgcn_mfma_f32_16x16x32_bf16(a[mi], bfr[ni], acc[mi][ni], 0, 0, 0);
        }
    }
    int col = lane & 15, rbase = (lane >> 4) * 4;
    #pragma unroll
    for (int mi = 0; mi < 4; mi++)
        #pragma unroll
        for (int ni = 0; ni < 4; ni++)
            #pragma unroll
            for (int r = 0; r < 4; r++) {
                int m = m0 + wm * 64 + mi * 16 + rbase + r;
                int v = n0 + wn * 64 + ni * 16 + col;
                int b = m & 31, t = m >> 5;
                out[((size_t)(b * 64 + t)) * 32000 + v] = acc[mi][ni][r];
            }
}

// ---------------- launch ----------------
extern "C" void kernel_launch(void* const* d_in, const int* in_sizes, int n_in,
                              void* d_out, int out_size, void* d_ws, size_t ws_size,
                              hipStream_t stream) {
    const float* img    = (const float*)d_in[0];
    const int*   toks   = (const int*)d_in[1];
    const float* embed  = (const float*)d_in[2];
    const float* W_ctx  = (const float*)d_in[3];
    const float* W_mix  = (const float*)d_in[4];
    const float* ln_g   = (const float*)d_in[5];
    const float* ln_b   = (const float*)d_in[6];
    const float* W_ih   = (const float*)d_in[7];
    const float* W_hh   = (const float*)d_in[8];
    const float* b_ih   = (const float*)d_in[9];
    const float* b_hh   = (const float*)d_in[10];
    const float* W_head = (const float*)d_in[11];
    const float* W_img  = (const float*)d_in[12];
    const float* W_hid  = (const float*)d_in[13];
    const float* w_sc   = (const float*)d_in[14];
    const float* W_h0   = (const float*)d_in[15];
    const float* b_h0   = (const float*)d_in[16];
    const float* W_c0   = (const float*)d_in[17];
    const float* b_c0   = (const float*)d_in[18];

    float* out = (float*)d_out;
    float* ws  = (float*)d_ws;
    unsigned short* Wbf     = (unsigned short*)(ws + WS_WBF);
    unsigned short* imgbf   = (unsigned short*)(ws + WS_IMGBF);
    unsigned short* wctxbf  = (unsigned short*)(ws + WS_WCTXBF);
    unsigned short* wimgbf  = (unsigned short*)(ws + WS_WIMGBF);
    unsigned short* wmixRbf = (unsigned short*)(ws + WS_WMIXRBF);
    float* imgE   = ws + WS_IMGE;     // then imgEM
    unsigned short* imgEbf = (unsigned short*)(ws + WS_IMGEBF);
    float* proj   = ws + WS_PROJ;
    float* g      = ws + WS_G;
    float* H      = ws + WS_H;
    float* C      = ws + WS_C;
    float* XN     = ws + WS_XN;
    unsigned* bar = (unsigned*)(ws + WS_BAR);
    unsigned short* h2bf = (unsigned short*)(ws + WS_H2BF);

    // prep: casts
    k_castpad<<<1664, 256, 0, stream>>>(img,    imgbf,   1568, 1664, 2048, 2048, 0);
    k_castpad<<<512,  256, 0, stream>>>(W_ctx,  wctxbf,  512,  512,  2048, 2048, 0);
    k_castpad<<<128,  256, 0, stream>>>(W_img,  wimgbf,  128,  128,  2048, 2048, 0);
    k_castpad<<<128,  256, 0, stream>>>(W_mix,  wmixRbf, 512,  512,  512,  1024, 512);
    k_castpad<<<8000, 256, 0, stream>>>(W_head, Wbf,     32000, 32000, 512, 512, 0);
    // prep: bf16 MFMA GEMMs (attention path)
    k_gemm<<<dim3(4, 13), 256, 0, stream>>>(imgbf, wctxbf, imgE, 512, 2048);
    k_gemm<<<dim3(1, 13), 256, 0, stream>>>(imgbf, wimgbf, proj, 128, 2048);
    k_castpad<<<416, 256, 0, stream>>>(imgE, imgEbf, 1664, 1664, 512, 512, 0);
    k_gemm<<<dim3(4, 13), 256, 0, stream>>>(imgEbf, wmixRbf, imgE /*imgEM*/, 512, 512);
    // prep: init state
    k_gmean<<<32, 256, 0, stream>>>(img, g);
    k_h0c0<<<64, 256, 0, stream>>>(g, W_h0, b_h0, W_c0, b_c0, H, C);
    hipMemsetAsync(bar, 0, 256, stream);

    // recurrence (2 grid barriers per step, no fences)
    k_persist<<<NBLK, 1024, 0, stream>>>(toks, embed, ln_g, ln_b, b_ih, b_hh, w_sc,
                                         W_hid, W_mix, W_hh, W_ih, proj, imgE /*imgEM*/,
                                         H, C, XN, bar, h2bf);

    // deferred batched head GEMM
    k_head<<<dim3(250, 16), 256, 0, stream>>>(h2bf, Wbf, out);
}

// Round 4
// 4987.308 us; speedup vs baseline: 5.2185x; 1.6464x over previous
//
#include <hip/hip_runtime.h>

// sizes
#define NV 32000
#define NT 64
#define NBLK 96u

typedef unsigned long long ull;
typedef unsigned short ushort;
typedef __attribute__((ext_vector_type(8))) short v8s;
typedef __attribute__((ext_vector_type(4))) float v4f;

// ws offsets (floats)
#define WS_WBF     0          // ushort [32000][512]
#define WS_IMGBF   8192000    // ushort [1664][2048]  (prep only; later overlaid)
#define WS_WHHBF   8192000    //   overlay after prep GEMMs: ushort [2048][512]
#define WS_WIHBF   8716288    //   ushort [2048][512]
#define WS_WMIXLBF 9240576    //   ushort [512][512]
#define WS_WHIDBF  9371648    //   ushort [128][512]
#define WS_WCTXBF  9895936    // ushort [512][2048]
#define WS_WIMGBF  10420224   // ushort [128][2048]
#define WS_WMIXRBF 10551296   // ushort [512][512]
#define WS_IMGE    10682368   // f32 [1664][512]  (imgE, then imgEM overwrites)
#define WS_IMGEBF  11534336   // ushort [1664][512]
#define WS_PROJ    11960320   // f32 [1664][128]
#define WS_G       12173312   // f32 [32][2048]
#define WS_H       12238848   // f32 [32][512]
#define WS_C       12255232   // f32 [32][512]
#define WS_XN      12271616   // f32 [32][512]
#define WS_BAR     12288000   // counter
#define WS_H2BF    12288064   // ushort [2048][512]

__device__ __forceinline__ float fsig(float x) {
    x = fminf(fmaxf(x, -30.f), 30.f);
    return 1.f / (1.f + __expf(-x));
}
__device__ __forceinline__ float ftanh(float x) {
    x = fminf(fmaxf(x, -15.f), 15.f);
    float e = __expf(2.f * x);
    return (e - 1.f) / (e + 1.f);
}
__device__ __forceinline__ unsigned short f2bf(float f) {
    union { float f; unsigned int u; } v; v.f = f;
    unsigned int u = v.u;
    return (unsigned short)((u + 0x7FFFu + ((u >> 16) & 1u)) >> 16);
}
__device__ __forceinline__ float bf_lo(unsigned u) { return __uint_as_float(u << 16); }
__device__ __forceinline__ float bf_hi(unsigned u) { return __uint_as_float(u & 0xffff0000u); }

// ---------------- prep kernels ----------------

// out[r][k] (r<Rpad) = (r<R) ? bf16(in[r*ldi + off + k]) : 0    (K mult of 8)
__global__ __launch_bounds__(256) void k_castpad(const float* __restrict__ in,
        ushort* __restrict__ out, int R, int Rpad, int K, int ldi, int off) {
    size_t i = ((size_t)blockIdx.x * 256 + threadIdx.x) * 8;
    if (i >= (size_t)Rpad * K) return;
    int r = (int)(i / K), k = (int)(i % K);
    uint4 o = {0, 0, 0, 0};
    if (r < R) {
        const float* p = in + (size_t)r * ldi + off + k;
        float4 a = *(const float4*)(p);
        float4 b = *(const float4*)(p + 4);
        o.x = (unsigned)f2bf(a.x) | ((unsigned)f2bf(a.y) << 16);
        o.y = (unsigned)f2bf(a.z) | ((unsigned)f2bf(a.w) << 16);
        o.z = (unsigned)f2bf(b.x) | ((unsigned)f2bf(b.y) << 16);
        o.w = (unsigned)f2bf(b.z) | ((unsigned)f2bf(b.w) << 16);
    }
    *(uint4*)(out + i) = o;
}

// C[m][n] = sum_k A[m][k]*B[n][k]; M=gridDim.y*128 (padded), N=gridDim.x*128, K mult of 64
__global__ __launch_bounds__(256) void k_gemm(const ushort* __restrict__ A,
        const ushort* __restrict__ B, float* __restrict__ C, int N, int K) {
    __shared__ ushort Al[128][72];
    __shared__ ushort Bl[128][72];
    int n0 = blockIdx.x * 128, m0 = blockIdx.y * 128;
    int tid = threadIdx.x, lane = tid & 63, wid = tid >> 6;
    int wm = wid >> 1, wn = wid & 1;
    v4f acc[4][4] = {};
    for (int kt = 0; kt < K; kt += 64) {
        __syncthreads();
        #pragma unroll
        for (int i = 0; i < 4; i++) {
            int idx = i * 256 + tid;
            int row = idx >> 3, c8 = (idx & 7) * 8;
            *(uint4*)&Al[row][c8] = *(const uint4*)&A[(size_t)(m0 + row) * K + kt + c8];
            *(uint4*)&Bl[row][c8] = *(const uint4*)&B[(size_t)(n0 + row) * K + kt + c8];
        }
        __syncthreads();
        #pragma unroll
        for (int kk = 0; kk < 2; kk++) {
            v8s a[4], bfr[4];
            int ko = kk * 32 + (lane >> 4) * 8;
            #pragma unroll
            for (int mi = 0; mi < 4; mi++)
                a[mi] = *(const v8s*)&Al[wm * 64 + mi * 16 + (lane & 15)][ko];
            #pragma unroll
            for (int ni = 0; ni < 4; ni++)
                bfr[ni] = *(const v8s*)&Bl[wn * 64 + ni * 16 + (lane & 15)][ko];
            #pragma unroll
            for (int mi = 0; mi < 4; mi++)
                #pragma unroll
                for (int ni = 0; ni < 4; ni++)
                    acc[mi][ni] = __builtin_amdgcn_mfma_f32_16x16x32_bf16(a[mi], bfr[ni], acc[mi][ni], 0, 0, 0);
        }
    }
    int col = lane & 15, rbase = (lane >> 4) * 4;
    #pragma unroll
    for (int mi = 0; mi < 4; mi++)
        #pragma unroll
        for (int ni = 0; ni < 4; ni++)
            #pragma unroll
            for (int r = 0; r < 4; r++) {
                int m = m0 + wm * 64 + mi * 16 + rbase + r;
                int v = n0 + wn * 64 + ni * 16 + col;
                C[(size_t)m * N + v] = acc[mi][ni][r];
            }
}

__global__ __launch_bounds__(256) void k_gmean(const float* __restrict__ img,
                                               float* __restrict__ g) {
    int b = blockIdx.x;
    for (int d = threadIdx.x; d < 2048; d += 256) {
        float s = 0.f;
        for (int ss = 0; ss < 49; ss++) s += img[((size_t)(b * 49 + ss)) * 2048 + d];
        g[b * 2048 + d] = s * (1.f / 49.f);
    }
}

__global__ __launch_bounds__(256) void k_h0c0(const float* __restrict__ g,
        const float* __restrict__ Wh0, const float* __restrict__ bh0,
        const float* __restrict__ Wc0, const float* __restrict__ bc0,
        float* __restrict__ h0, float* __restrict__ c0) {
    int b = blockIdx.x >> 1, m = blockIdx.x & 1;
    __shared__ float gs[2048];
    for (int d = threadIdx.x; d < 2048; d += 256) gs[d] = g[b * 2048 + d];
    __syncthreads();
    const float* W = m ? Wc0 : Wh0;
    const float* bb = m ? bc0 : bh0;
    float* out = m ? c0 : h0;
    for (int r = threadIdx.x; r < 512; r += 256) {
        float acc = 0.f;
        const float* wr = W + (size_t)r * 2048;
        for (int d = 0; d < 2048; d += 4) {
            float4 w = *(const float4*)(wr + d);
            acc += w.x * gs[d] + w.y * gs[d + 1] + w.z * gs[d + 2] + w.w * gs[d + 3];
        }
        out[b * 512 + r] = ftanh(acc + bb[r]) * 0.5f;
    }
}

// ---------------- persistent recurrence ----------------
// NO fences: weights (bf16, ~6.7MB chip-wide, ~3.2MB/XCD) stay L2-resident.
// Cross-block data moves through relaxed agent-scope atomics only.

__device__ __forceinline__ void gridbar(unsigned* bar, unsigned target) {
    __syncthreads();
    if (threadIdx.x == 0) {
        __hip_atomic_fetch_add(bar, 1u, __ATOMIC_RELAXED, __HIP_MEMORY_SCOPE_AGENT);
        while (__hip_atomic_load(bar, __ATOMIC_RELAXED, __HIP_MEMORY_SCOPE_AGENT) < target)
            __builtin_amdgcn_s_sleep(1);
    }
    __syncthreads();
}

union SMem {
    struct {                       // gates role (blocks 0..63)
        float hs[8][512];
        float xn[8][512];
        float red[4][1024];
        float red2[1024];
    } g;
    struct {                       // attention role (blocks 64..95)
        float hb[512];
        float ebs[512];
        float php[8][128];
        float ph[128];
        float scp[64][16];
        float wsm[64];
        float xps[2][512];
        float wred[8][2];
        float bc[2];
    } a;
};

__global__ __launch_bounds__(1024) void k_persist(
        const int* __restrict__ toks, const float* __restrict__ embed,
        const float* __restrict__ lng, const float* __restrict__ lnb,
        const float* __restrict__ bih, const float* __restrict__ bhh,
        const float* __restrict__ wsc, const ushort* __restrict__ whidbf,
        const ushort* __restrict__ wmixLbf, const ushort* __restrict__ whhbf,
        const ushort* __restrict__ wihbf, const float* __restrict__ proj,
        const float* __restrict__ imgEM, float* __restrict__ H,
        const float* __restrict__ C0, float* __restrict__ XN,
        unsigned* __restrict__ BAR, ushort* __restrict__ h2bf) {
    __shared__ SMem sm;
    int blk = blockIdx.x, tid = threadIdx.x;
    bool is_gates = (blk < 64);

    int jc = blk >> 2, bh = blk & 3, b0 = bh * 8;
    int jl = tid & 31, bi = (tid >> 5) & 7, kh = tid >> 8;
    float c_reg = 0.f;
    if (is_gates && tid < 256)
        c_reg = C0[(b0 + (tid >> 5)) * 512 + jc * 32 + (tid & 31)];
    int b = blk - 64;

    float ghp[4] = {0.f, 0.f, 0.f, 0.f};

    for (int t = 0; t < NT; t++) {
        // ================= phase 1 =================
        if (is_gates) {
            const ull* Hq = (const ull*)H + (size_t)b0 * 256;
            ull* hq = (ull*)sm.g.hs;
            for (int i = tid; i < 2048; i += 1024)
                hq[i] = __hip_atomic_load((ull*)&Hq[i], __ATOMIC_RELAXED, __HIP_MEMORY_SCOPE_AGENT);
            __syncthreads();
            const float* hrow = sm.g.hs[bi] + kh * 128;
            int r0 = jc * 32 + jl;
            const ushort* w0 = whhbf + ((size_t)(0    + r0)) * 512 + kh * 128;
            const ushort* w1 = whhbf + ((size_t)(512  + r0)) * 512 + kh * 128;
            const ushort* w2 = whhbf + ((size_t)(1024 + r0)) * 512 + kh * 128;
            const ushort* w3 = whhbf + ((size_t)(1536 + r0)) * 512 + kh * 128;
            float a0 = 0.f, a1 = 0.f, a2 = 0.f, a3 = 0.f;
            #pragma unroll 4
            for (int k = 0; k < 128; k += 8) {
                float4 ha = *(const float4*)(hrow + k);
                float4 hb = *(const float4*)(hrow + k + 4);
                uint4 q0 = *(const uint4*)(w0 + k);
                uint4 q1 = *(const uint4*)(w1 + k);
                uint4 q2 = *(const uint4*)(w2 + k);
                uint4 q3 = *(const uint4*)(w3 + k);
                a0 += bf_lo(q0.x)*ha.x + bf_hi(q0.x)*ha.y + bf_lo(q0.y)*ha.z + bf_hi(q0.y)*ha.w
                    + bf_lo(q0.z)*hb.x + bf_hi(q0.z)*hb.y + bf_lo(q0.w)*hb.z + bf_hi(q0.w)*hb.w;
                a1 += bf_lo(q1.x)*ha.x + bf_hi(q1.x)*ha.y + bf_lo(q1.y)*ha.z + bf_hi(q1.y)*ha.w
                    + bf_lo(q1.z)*hb.x + bf_hi(q1.z)*hb.y + bf_lo(q1.w)*hb.z + bf_hi(q1.w)*hb.w;
                a2 += bf_lo(q2.x)*ha.x + bf_hi(q2.x)*ha.y + bf_lo(q2.y)*ha.z + bf_hi(q2.y)*ha.w
                    + bf_lo(q2.z)*hb.x + bf_hi(q2.z)*hb.y + bf_lo(q2.w)*hb.z + bf_hi(q2.w)*hb.w;
                a3 += bf_lo(q3.x)*ha.x + bf_hi(q3.x)*ha.y + bf_lo(q3.y)*ha.z + bf_hi(q3.y)*ha.w
                    + bf_lo(q3.z)*hb.x + bf_hi(q3.z)*hb.y + bf_lo(q3.w)*hb.z + bf_hi(q3.w)*hb.w;
            }
            if (kh == 0) {
                a0 += bih[r0] + bhh[r0];
                a1 += bih[512 + r0] + bhh[512 + r0];
                a2 += bih[1024 + r0] + bhh[1024 + r0];
                a3 += bih[1536 + r0] + bhh[1536 + r0];
            }
            ghp[0] = a0; ghp[1] = a1; ghp[2] = a2; ghp[3] = a3;
        } else {
            int tok = toks[b * 64 + t];
            if (tid < 256) {
                ull v = __hip_atomic_load((ull*)H + b * 256 + tid, __ATOMIC_RELAXED, __HIP_MEMORY_SCOPE_AGENT);
                ((ull*)sm.a.hb)[tid] = v;
            } else if (tid < 768) {
                int k = tid - 256;
                sm.a.ebs[k] = (tok == 0) ? 0.f : embed[(size_t)tok * 512 + k];
            }
            __syncthreads();
            {   // ph partials (bf16 W_hid)
                int a = tid & 127, kq = tid >> 7;
                const ushort* wr = whidbf + (size_t)a * 512 + kq * 64;
                const float* hp = sm.a.hb + kq * 64;
                float p = 0.f;
                #pragma unroll 4
                for (int k = 0; k < 64; k += 8) {
                    float4 ha = *(const float4*)(hp + k);
                    float4 hb = *(const float4*)(hp + k + 4);
                    uint4 q = *(const uint4*)(wr + k);
                    p += bf_lo(q.x)*ha.x + bf_hi(q.x)*ha.y + bf_lo(q.y)*ha.z + bf_hi(q.y)*ha.w
                       + bf_lo(q.z)*hb.x + bf_hi(q.z)*hb.y + bf_lo(q.w)*hb.z + bf_hi(q.w)*hb.w;
                }
                sm.a.php[kq][a] = p;
            }
            __syncthreads();
            if (tid < 128) {
                float p = 0.f;
                #pragma unroll
                for (int kq = 0; kq < 8; kq++) p += sm.a.php[kq][tid];
                sm.a.ph[tid] = p;
            }
            __syncthreads();
            {   // score partials
                int s = tid >> 4, aq = tid & 15;
                float p = 0.f;
                if (s < 49) {
                    const float* pr = proj + (size_t)(b * 49 + s) * 128 + aq * 8;
                    #pragma unroll
                    for (int a = 0; a < 8; a++)
                        p += ftanh(pr[a] + sm.a.ph[aq * 8 + a]) * wsc[aq * 8 + a];
                }
                sm.a.scp[s][aq] = p;
            }
            __syncthreads();
            if (tid < 64) {
                float v = 0.f;
                #pragma unroll
                for (int q = 0; q < 16; q++) v += sm.a.scp[tid][q];
                if (tid >= 49) v = -1e30f;
                float m = v;
                for (int o = 32; o > 0; o >>= 1) m = fmaxf(m, __shfl_xor(m, o));
                float e = (tid < 49) ? __expf(v - m) : 0.f;
                float su = e;
                for (int o = 32; o > 0; o >>= 1) su += __shfl_xor(su, o);
                sm.a.wsm[tid] = e / su;
            }
            __syncthreads();
            {   // x partial: emb @ WmixL (bf16) + sum_s w_s imgEM
                int e = tid & 511, sh = tid >> 9;
                float xp = 0.f;
                const ushort* wrow = wmixLbf + (size_t)e * 512 + sh * 256;
                const float* ep = sm.a.ebs + sh * 256;
                #pragma unroll 4
                for (int k = 0; k < 256; k += 8) {
                    float4 ea = *(const float4*)(ep + k);
                    float4 eb = *(const float4*)(ep + k + 4);
                    uint4 q = *(const uint4*)(wrow + k);
                    xp += bf_lo(q.x)*ea.x + bf_hi(q.x)*ea.y + bf_lo(q.y)*ea.z + bf_hi(q.y)*ea.w
                        + bf_lo(q.z)*eb.x + bf_hi(q.z)*eb.y + bf_lo(q.w)*eb.z + bf_hi(q.w)*eb.w;
                }
                int s0 = sh * 25, s1 = sh ? 49 : 25;
                for (int s = s0; s < s1; s++)
                    xp += sm.a.wsm[s] * imgEM[((size_t)(b * 49 + s)) * 512 + e];
                sm.a.xps[sh][e] = xp;
            }
            __syncthreads();
            if (tid < 512) {
                float x = fmaxf(sm.a.xps[0][tid] + sm.a.xps[1][tid], 0.f);
                float s = x, s2 = x * x;
                for (int o = 32; o > 0; o >>= 1) { s += __shfl_xor(s, o); s2 += __shfl_xor(s2, o); }
                if ((tid & 63) == 0) { sm.a.wred[tid >> 6][0] = s; sm.a.wred[tid >> 6][1] = s2; }
            }
            __syncthreads();
            if (tid == 0) {
                float s = 0.f, s2 = 0.f;
                #pragma unroll
                for (int w = 0; w < 8; w++) { s += sm.a.wred[w][0]; s2 += sm.a.wred[w][1]; }
                float mu = s * (1.f / 512.f);
                float var = s2 * (1.f / 512.f) - mu * mu;
                sm.a.bc[0] = mu; sm.a.bc[1] = rsqrtf(var + 1e-5f);
            }
            __syncthreads();
            if (tid < 512) {
                float x = fmaxf(sm.a.xps[0][tid] + sm.a.xps[1][tid], 0.f);
                float xn = (x - sm.a.bc[0]) * sm.a.bc[1] * lng[tid] + lnb[tid] + sm.a.ebs[tid];
                __hip_atomic_store((unsigned*)&XN[b * 512 + tid], __float_as_uint(xn),
                                   __ATOMIC_RELAXED, __HIP_MEMORY_SCOPE_AGENT);
            }
        }
        gridbar(BAR, NBLK * (unsigned)(2 * t + 1));

        // ================= phase 2 =================
        if (is_gates) {
            const ull* Xq = (const ull*)XN + (size_t)b0 * 256;
            ull* xq = (ull*)sm.g.xn;
            for (int i = tid; i < 2048; i += 1024)
                xq[i] = __hip_atomic_load((ull*)&Xq[i], __ATOMIC_RELAXED, __HIP_MEMORY_SCOPE_AGENT);
            __syncthreads();
            const float* xrow = sm.g.xn[bi] + kh * 128;
            int r0 = jc * 32 + jl;
            const ushort* w0 = wihbf + ((size_t)(0    + r0)) * 512 + kh * 128;
            const ushort* w1 = wihbf + ((size_t)(512  + r0)) * 512 + kh * 128;
            const ushort* w2 = wihbf + ((size_t)(1024 + r0)) * 512 + kh * 128;
            const ushort* w3 = wihbf + ((size_t)(1536 + r0)) * 512 + kh * 128;
            float a0 = ghp[0], a1 = ghp[1], a2 = ghp[2], a3 = ghp[3];
            #pragma unroll 4
            for (int k = 0; k < 128; k += 8) {
                float4 xa = *(const float4*)(xrow + k);
                float4 xb = *(const float4*)(xrow + k + 4);
                uint4 q0 = *(const uint4*)(w0 + k);
                uint4 q1 = *(const uint4*)(w1 + k);
                uint4 q2 = *(const uint4*)(w2 + k);
                uint4 q3 = *(const uint4*)(w3 + k);
                a0 += bf_lo(q0.x)*xa.x + bf_hi(q0.x)*xa.y + bf_lo(q0.y)*xa.z + bf_hi(q0.y)*xa.w
                    + bf_lo(q0.z)*xb.x + bf_hi(q0.z)*xb.y + bf_lo(q0.w)*xb.z + bf_hi(q0.w)*xb.w;
                a1 += bf_lo(q1.x)*xa.x + bf_hi(q1.x)*xa.y + bf_lo(q1.y)*xa.z + bf_hi(q1.y)*xa.w
                    + bf_lo(q1.z)*xb.x + bf_hi(q1.z)*xb.y + bf_lo(q1.w)*xb.z + bf_hi(q1.w)*xb.w;
                a2 += bf_lo(q2.x)*xa.x + bf_hi(q2.x)*xa.y + bf_lo(q2.y)*xa.z + bf_hi(q2.y)*xa.w
                    + bf_lo(q2.z)*xb.x + bf_hi(q2.z)*xb.y + bf_lo(q2.w)*xb.z + bf_hi(q2.w)*xb.w;
                a3 += bf_lo(q3.x)*xa.x + bf_hi(q3.x)*xa.y + bf_lo(q3.y)*xa.z + bf_hi(q3.y)*xa.w
                    + bf_lo(q3.z)*xb.x + bf_hi(q3.z)*xb.y + bf_lo(q3.w)*xb.z + bf_hi(q3.w)*xb.w;
            }
            int base = bi * 32 + jl;
            sm.g.red[kh][0 * 256 + base] = a0;
            sm.g.red[kh][1 * 256 + base] = a1;
            sm.g.red[kh][2 * 256 + base] = a2;
            sm.g.red[kh][3 * 256 + base] = a3;
            __syncthreads();
            sm.g.red2[tid] = sm.g.red[0][tid] + sm.g.red[1][tid] + sm.g.red[2][tid] + sm.g.red[3][tid];
            __syncthreads();
            if (tid < 256) {
                float gi_ = sm.g.red2[tid];
                float gf_ = sm.g.red2[256 + tid];
                float gg_ = sm.g.red2[512 + tid];
                float go_ = sm.g.red2[768 + tid];
                float c2 = fsig(gf_) * c_reg + fsig(gi_) * ftanh(gg_);
                float h2 = fsig(go_) * ftanh(c2);
                c_reg = c2;
                int bb2 = b0 + (tid >> 5), j = jc * 32 + (tid & 31);
                __hip_atomic_store((unsigned*)&H[bb2 * 512 + j], __float_as_uint(h2),
                                   __ATOMIC_RELAXED, __HIP_MEMORY_SCOPE_AGENT);
                h2bf[(size_t)(t * 32 + bb2) * 512 + j] = f2bf(h2);
            }
        }
        gridbar(BAR, NBLK * (unsigned)(2 * t + 2));
    }
}

// ---------------- deferred head GEMM ----------------
__global__ __launch_bounds__(256) void k_head(const ushort* __restrict__ h2bf,
        const ushort* __restrict__ Wbf, float* __restrict__ out) {
    __shared__ ushort Al[128][72];
    __shared__ ushort Bl[128][72];
    int n0 = blockIdx.x * 128, m0 = blockIdx.y * 128;
    int tid = threadIdx.x, lane = tid & 63, wid = tid >> 6;
    int wm = wid >> 1, wn = wid & 1;
    v4f acc[4][4] = {};
    for (int kt = 0; kt < 512; kt += 64) {
        __syncthreads();
        #pragma unroll
        for (int i = 0; i < 4; i++) {
            int idx = i * 256 + tid;
            int row = idx >> 3, c8 = (idx & 7) * 8;
            *(uint4*)&Al[row][c8] = *(const uint4*)&h2bf[(size_t)(m0 + row) * 512 + kt + c8];
            *(uint4*)&Bl[row][c8] = *(const uint4*)&Wbf[(size_t)(n0 + row) * 512 + kt + c8];
        }
        __syncthreads();
        #pragma unroll
        for (int kk = 0; kk < 2; kk++) {
            v8s a[4], bfr[4];
            int ko = kk * 32 + (lane >> 4) * 8;
            #pragma unroll
            for (int mi = 0; mi < 4; mi++)
                a[mi] = *(const v8s*)&Al[wm * 64 + mi * 16 + (lane & 15)][ko];
            #pragma unroll
            for (int ni = 0; ni < 4; ni++)
                bfr[ni] = *(const v8s*)&Bl[wn * 64 + ni * 16 + (lane & 15)][ko];
            #pragma unroll
            for (int mi = 0; mi < 4; mi++)
                #pragma unroll
                for (int ni = 0; ni < 4; ni++)
                    acc[mi][ni] = __builtin_amdgcn_mfma_f32_16x16x32_bf16(a[mi], bfr[ni], acc[mi][ni], 0, 0, 0);
        }
    }
    int col = lane & 15, rbase = (lane >> 4) * 4;
    #pragma unroll
    for (int mi = 0; mi < 4; mi++)
        #pragma unroll
        for (int ni = 0; ni < 4; ni++)
            #pragma unroll
            for (int r = 0; r < 4; r++) {
                int m = m0 + wm * 64 + mi * 16 + rbase + r;
                int v = n0 + wn * 64 + ni * 16 + col;
                int b = m & 31, t = m >> 5;
                out[((size_t)(b * 64 + t)) * 32000 + v] = acc[mi][ni][r];
            }
}

// ---------------- launch ----------------
extern "C" void kernel_launch(void* const* d_in, const int* in_sizes, int n_in,
                              void* d_out, int out_size, void* d_ws, size_t ws_size,
                              hipStream_t stream) {
    const float* img    = (const float*)d_in[0];
    const int*   toks   = (const int*)d_in[1];
    const float* embed  = (const float*)d_in[2];
    const float* W_ctx  = (const float*)d_in[3];
    const float* W_mix  = (const float*)d_in[4];
    const float* ln_g   = (const float*)d_in[5];
    const float* ln_b   = (const float*)d_in[6];
    const float* W_ih   = (const float*)d_in[7];
    const float* W_hh   = (const float*)d_in[8];
    const float* b_ih   = (const float*)d_in[9];
    const float* b_hh   = (const float*)d_in[10];
    const float* W_head = (const float*)d_in[11];
    const float* W_img  = (const float*)d_in[12];
    const float* W_hid  = (const float*)d_in[13];
    const float* w_sc   = (const float*)d_in[14];
    const float* W_h0   = (const float*)d_in[15];
    const float* b_h0   = (const float*)d_in[16];
    const float* W_c0   = (const float*)d_in[17];
    const float* b_c0   = (const float*)d_in[18];

    float* out = (float*)d_out;
    float* ws  = (float*)d_ws;
    ushort* Wbf     = (ushort*)(ws + WS_WBF);
    ushort* imgbf   = (ushort*)(ws + WS_IMGBF);
    ushort* whhbf   = (ushort*)(ws + WS_WHHBF);
    ushort* wihbf   = (ushort*)(ws + WS_WIHBF);
    ushort* wmixLbf = (ushort*)(ws + WS_WMIXLBF);
    ushort* whidbf  = (ushort*)(ws + WS_WHIDBF);
    ushort* wctxbf  = (ushort*)(ws + WS_WCTXBF);
    ushort* wimgbf  = (ushort*)(ws + WS_WIMGBF);
    ushort* wmixRbf = (ushort*)(ws + WS_WMIXRBF);
    float* imgE   = ws + WS_IMGE;     // then imgEM
    ushort* imgEbf = (ushort*)(ws + WS_IMGEBF);
    float* proj   = ws + WS_PROJ;
    float* g      = ws + WS_G;
    float* H      = ws + WS_H;
    float* C      = ws + WS_C;
    float* XN     = ws + WS_XN;
    unsigned* bar = (unsigned*)(ws + WS_BAR);
    ushort* h2bf  = (ushort*)(ws + WS_H2BF);

    // prep phase A: casts + attention-path GEMMs (use imgbf region)
    k_castpad<<<1664, 256, 0, stream>>>(img,    imgbf,   1568, 1664, 2048, 2048, 0);
    k_castpad<<<512,  256, 0, stream>>>(W_ctx,  wctxbf,  512,  512,  2048, 2048, 0);
    k_castpad<<<128,  256, 0, stream>>>(W_img,  wimgbf,  128,  128,  2048, 2048, 0);
    k_castpad<<<128,  256, 0, stream>>>(W_mix,  wmixRbf, 512,  512,  512,  1024, 512);
    k_castpad<<<8000, 256, 0, stream>>>(W_head, Wbf,     32000, 32000, 512, 512, 0);
    k_gemm<<<dim3(4, 13), 256, 0, stream>>>(imgbf, wctxbf, imgE, 512, 2048);
    k_gemm<<<dim3(1, 13), 256, 0, stream>>>(imgbf, wimgbf, proj, 128, 2048);
    k_castpad<<<416, 256, 0, stream>>>(imgE, imgEbf, 1664, 1664, 512, 512, 0);
    k_gemm<<<dim3(4, 13), 256, 0, stream>>>(imgEbf, wmixRbf, imgE /*imgEM*/, 512, 512);

    // prep phase B: imgbf dead now — overlay the persist-kernel bf16 weights
    k_castpad<<<512, 256, 0, stream>>>(W_hh,  whhbf,   2048, 2048, 512, 512, 0);
    k_castpad<<<512, 256, 0, stream>>>(W_ih,  wihbf,   2048, 2048, 512, 512, 0);
    k_castpad<<<128, 256, 0, stream>>>(W_mix, wmixLbf, 512,  512,  512, 1024, 0);
    k_castpad<<<32,  256, 0, stream>>>(W_hid, whidbf,  128,  128,  512, 512, 0);

    // prep: init state
    k_gmean<<<32, 256, 0, stream>>>(img, g);
    k_h0c0<<<64, 256, 0, stream>>>(g, W_h0, b_h0, W_c0, b_c0, H, C);
    hipMemsetAsync(bar, 0, 256, stream);

    // recurrence (2 grid barriers per step, no fences, L2-resident bf16 weights)
    k_persist<<<NBLK, 1024, 0, stream>>>(toks, embed, ln_g, ln_b, b_ih, b_hh, w_sc,
                                         whidbf, wmixLbf, whhbf, wihbf, proj,
                                         imgE /*imgEM*/, H, C, XN, bar, h2bf);

    // deferred batched head GEMM
    k_head<<<dim3(250, 16), 256, 0, stream>>>(h2bf, Wbf, out);
}

// Round 6
// 2061.295 us; speedup vs baseline: 12.6261x; 2.4195x over previous
//
#include <hip/hip_runtime.h>

#define NV 32000
#define NT 64
#define NBLK 160u

typedef unsigned long long ull;
typedef unsigned short ushort;
typedef __attribute__((ext_vector_type(8))) short v8s;
typedef __attribute__((ext_vector_type(4))) float v4f;

// persistent ws layout (float offsets; ushort regions = count/2 floats)
#define WS_WBF     0          // ushort [32000][512]           -> 8192000
#define WS_H2BF    8192000    // ushort [2048][512]  (524288)  -> 8716288
#define WS_IMGEM   8716288    // f32 [1664][512]     (851968)  -> 9568256
#define WS_PROJ    9568256    // f32 [1664][128]     (212992)  -> 9781248
#define WS_EMBM    9781248    // f32 [2048][512]     (1048576) -> 10829824
#define WS_WHHBF   10829824   // ushort [2048][512]  (524288)  -> 11354112
#define WS_WIHBF   11354112   // ushort [2048][512]  (524288)  -> 11878400
#define WS_WHIDBF  11878400   // ushort [128][512]   (32768)   -> 11911168
#define WS_H       11911168   // f32 [32][512]       (16384)   -> 11927552
#define WS_XN      11927552   // f32 [32][512]       (16384)   -> 11943936
#define WS_C       11943936   // f32 [32][512]       (16384)   -> 11960320
#define WS_BAR     11960320   // counter             (64)      -> 11960384
#define WS_G       11960384   // f32 [32][2048]      (65536)   -> 12025920
// prep scratch (inside Wbf slot [0,8192000); dead before W_head cast)
#define PS_IMGBF   0          // ushort [1664][2048] (1703936) -> 1703936
#define PS_WCTXBF  1703936    // ushort [512][2048]  (524288)  -> 2228224
#define PS_WIMGBF  2228224    // ushort [128][2048]  (131072)  -> 2359296
#define PS_WMIXRBF 2359296    // ushort [512][512]   (131072)  -> 2490368
#define PS_IMGE    2490368    // f32 [1664][512]     (851968)  -> 3342336
#define PS_IMGEBF  3342336    // ushort [1664][512]  (425984)  -> 3768320
#define PS_EMBG    3768320    // ushort [2048][512]  (524288)  -> 4292608
#define PS_WMIXLBF 4292608    // ushort [512][512]   (131072)  -> 4423680

__device__ __forceinline__ float fsig(float x) {
    x = fminf(fmaxf(x, -30.f), 30.f);
    return 1.f / (1.f + __expf(-x));
}
__device__ __forceinline__ float ftanh(float x) {
    x = fminf(fmaxf(x, -15.f), 15.f);
    float e = __expf(2.f * x);
    return (e - 1.f) / (e + 1.f);
}
__device__ __forceinline__ unsigned short f2bf(float f) {
    union { float f; unsigned int u; } v; v.f = f;
    unsigned int u = v.u;
    return (unsigned short)((u + 0x7FFFu + ((u >> 16) & 1u)) >> 16);
}
__device__ __forceinline__ float bf_lo(unsigned u) { return __uint_as_float(u << 16); }
__device__ __forceinline__ float bf_hi(unsigned u) { return __uint_as_float(u & 0xffff0000u); }

// ---------------- prep kernels ----------------

__global__ __launch_bounds__(256) void k_castpad(const float* __restrict__ in,
        ushort* __restrict__ out, int R, int Rpad, int K, int ldi, int off) {
    size_t i = ((size_t)blockIdx.x * 256 + threadIdx.x) * 8;
    if (i >= (size_t)Rpad * K) return;
    int r = (int)(i / K), k = (int)(i % K);
    uint4 o = {0, 0, 0, 0};
    if (r < R) {
        const float* p = in + (size_t)r * ldi + off + k;
        float4 a = *(const float4*)(p);
        float4 b = *(const float4*)(p + 4);
        o.x = (unsigned)f2bf(a.x) | ((unsigned)f2bf(a.y) << 16);
        o.y = (unsigned)f2bf(a.z) | ((unsigned)f2bf(a.w) << 16);
        o.z = (unsigned)f2bf(b.x) | ((unsigned)f2bf(b.y) << 16);
        o.w = (unsigned)f2bf(b.z) | ((unsigned)f2bf(b.w) << 16);
    }
    *(uint4*)(out + i) = o;
}

// gather token embeddings: embG[(t*32+b)][k] = bf16(embed[tok]*(tok!=0))
__global__ __launch_bounds__(128) void k_embg(const int* __restrict__ toks,
        const float* __restrict__ embed, ushort* __restrict__ embG) {
    int row = blockIdx.x;
    int t = row >> 5, b = row & 31;
    int tok = toks[b * 64 + t];
    int e = threadIdx.x * 4;
    uint2 o = {0, 0};
    if (tok != 0) {
        float4 a = *(const float4*)&embed[(size_t)tok * 512 + e];
        o.x = (unsigned)f2bf(a.x) | ((unsigned)f2bf(a.y) << 16);
        o.y = (unsigned)f2bf(a.z) | ((unsigned)f2bf(a.w) << 16);
    }
    *(uint2*)&embG[(size_t)row * 512 + e] = o;
}

// C[m][n] = sum_k A[m][k]*B[n][k]
__global__ __launch_bounds__(256) void k_gemm(const ushort* __restrict__ A,
        const ushort* __restrict__ B, float* __restrict__ C, int N, int K) {
    __shared__ ushort Al[128][72];
    __shared__ ushort Bl[128][72];
    int n0 = blockIdx.x * 128, m0 = blockIdx.y * 128;
    int tid = threadIdx.x, lane = tid & 63, wid = tid >> 6;
    int wm = wid >> 1, wn = wid & 1;
    v4f acc[4][4] = {};
    for (int kt = 0; kt < K; kt += 64) {
        __syncthreads();
        #pragma unroll
        for (int i = 0; i < 4; i++) {
            int idx = i * 256 + tid;
            int row = idx >> 3, c8 = (idx & 7) * 8;
            *(uint4*)&Al[row][c8] = *(const uint4*)&A[(size_t)(m0 + row) * K + kt + c8];
            *(uint4*)&Bl[row][c8] = *(const uint4*)&B[(size_t)(n0 + row) * K + kt + c8];
        }
        __syncthreads();
        #pragma unroll
        for (int kk = 0; kk < 2; kk++) {
            v8s a[4], bfr[4];
            int ko = kk * 32 + (lane >> 4) * 8;
            #pragma unroll
            for (int mi = 0; mi < 4; mi++)
                a[mi] = *(const v8s*)&Al[wm * 64 + mi * 16 + (lane & 15)][ko];
            #pragma unroll
            for (int ni = 0; ni < 4; ni++)
                bfr[ni] = *(const v8s*)&Bl[wn * 64 + ni * 16 + (lane & 15)][ko];
            #pragma unroll
            for (int mi = 0; mi < 4; mi++)
                #pragma unroll
                for (int ni = 0; ni < 4; ni++)
                    acc[mi][ni] = __builtin_amdgcn_mfma_f32_16x16x32_bf16(a[mi], bfr[ni], acc[mi][ni], 0, 0, 0);
        }
    }
    int col = lane & 15, rbase = (lane >> 4) * 4;
    #pragma unroll
    for (int mi = 0; mi < 4; mi++)
        #pragma unroll
        for (int ni = 0; ni < 4; ni++)
            #pragma unroll
            for (int r = 0; r < 4; r++) {
                int m = m0 + wm * 64 + mi * 16 + rbase + r;
                int v = n0 + wn * 64 + ni * 16 + col;
                C[(size_t)m * N + v] = acc[mi][ni][r];
            }
}

__global__ __launch_bounds__(256) void k_gmean(const float* __restrict__ img,
                                               float* __restrict__ g) {
    int b = blockIdx.x;
    for (int d = threadIdx.x; d < 2048; d += 256) {
        float s = 0.f;
        for (int ss = 0; ss < 49; ss++) s += img[((size_t)(b * 49 + ss)) * 2048 + d];
        g[b * 2048 + d] = s * (1.f / 49.f);
    }
}

__global__ __launch_bounds__(256) void k_h0c0(const float* __restrict__ g,
        const float* __restrict__ Wh0, const float* __restrict__ bh0,
        const float* __restrict__ Wc0, const float* __restrict__ bc0,
        float* __restrict__ h0, float* __restrict__ c0) {
    int b = blockIdx.x >> 1, m = blockIdx.x & 1;
    __shared__ float gs[2048];
    for (int d = threadIdx.x; d < 2048; d += 256) gs[d] = g[b * 2048 + d];
    __syncthreads();
    const float* W = m ? Wc0 : Wh0;
    const float* bb = m ? bc0 : bh0;
    float* out = m ? c0 : h0;
    for (int r = threadIdx.x; r < 512; r += 256) {
        float acc = 0.f;
        const float* wr = W + (size_t)r * 2048;
        for (int d = 0; d < 2048; d += 4) {
            float4 w = *(const float4*)(wr + d);
            acc += w.x * gs[d] + w.y * gs[d + 1] + w.z * gs[d + 2] + w.w * gs[d + 3];
        }
        out[b * 512 + r] = ftanh(acc + bb[r]) * 0.5f;
    }
}

// ---------------- persistent recurrence ----------------
// Weights pinned in LDS (gates) or L2-resident (attn path).
// Cross-block data only through relaxed agent-scope atomics. No fences.

__device__ __forceinline__ void gridbar(unsigned* bar, unsigned target) {
    __syncthreads();
    if (threadIdx.x == 0) {
        __hip_atomic_fetch_add(bar, 1u, __ATOMIC_RELAXED, __HIP_MEMORY_SCOPE_AGENT);
        while (__hip_atomic_load(bar, __ATOMIC_RELAXED, __HIP_MEMORY_SCOPE_AGENT) < target)
            __builtin_amdgcn_s_sleep(1);
    }
    __syncthreads();
}

union SMem {
    struct {                       // gates role (blocks 0..127)
        ushort wh[16][520];        // W_hh rows, bf16, padded
        ushort wi[16][520];        // W_ih rows
        float hs[32][516];         // staged H (phase1) / XN (phase2)
        float red[2][16][32];      // kh partials
    } g;                           // 103424 B
    struct {                       // attention role (blocks 128..159)
        float hb[512];
        float ebs[512];
        float php[8][128];
        float ph[128];
        float scp[64][16];
        float wsm[64];
        float xps[2][512];
        float wred[8][2];
        float bc[2];
    } a;
};

__global__ __launch_bounds__(1024, 1) void k_persist(
        const int* __restrict__ toks, const float* __restrict__ embed,
        const float* __restrict__ lng, const float* __restrict__ lnb,
        const float* __restrict__ bih, const float* __restrict__ bhh,
        const float* __restrict__ wsc, const ushort* __restrict__ whidbf,
        const ushort* __restrict__ whhbf, const ushort* __restrict__ wihbf,
        const float* __restrict__ proj, const float* __restrict__ imgEM,
        const float* __restrict__ embM, float* __restrict__ H,
        const float* __restrict__ C0, float* __restrict__ XN,
        unsigned* __restrict__ BAR, ushort* __restrict__ h2bf) {
    __shared__ SMem sm;
    int blk = blockIdx.x, tid = threadIdx.x;
    bool is_gates = (blk < 128);
    int g = blk;                       // gates: j-chunk [g*4, g*4+4)
    int r = (tid >> 5) & 15, b = tid & 31, kh = tid >> 9;
    int ab = blk - 128;                // attn: batch index
    float c_reg = 0.f, bs0 = 0.f, bs1 = 0.f, bs2 = 0.f, bs3 = 0.f;
    float ghp = 0.f;

    if (is_gates) {
        // pin weight slice in LDS (once)
        int wr_ = tid >> 6, c8 = (tid & 63) * 8;      // 16 rows x 8 uint4
        int gate = wr_ >> 2, jj = wr_ & 3;
        size_t R = (size_t)(gate * 512 + g * 4 + jj) * 512 + c8;
        *(uint4*)&sm.g.wh[wr_][c8] = *(const uint4*)&whhbf[R];
        *(uint4*)&sm.g.wi[wr_][c8] = *(const uint4*)&wihbf[R];
        if (tid < 128) {
            int jl = tid >> 5, bb = tid & 31;
            int j = g * 4 + jl;
            c_reg = C0[bb * 512 + j];
            bs0 = bih[j] + bhh[j];
            bs1 = bih[512 + j] + bhh[512 + j];
            bs2 = bih[1024 + j] + bhh[1024 + j];
            bs3 = bih[1536 + j] + bhh[1536 + j];
        }
    }
    __syncthreads();

    for (int t = 0; t < NT; t++) {
        // ================= phase 1: Whh*h | attention+LN =================
        if (is_gates) {
            for (int i = tid; i < 8192; i += 1024) {
                int bb = i >> 8, off = i & 255;
                ull v = __hip_atomic_load((const ull*)H + (size_t)bb * 256 + off,
                                          __ATOMIC_RELAXED, __HIP_MEMORY_SCOPE_AGENT);
                *(ull*)&sm.g.hs[bb][off * 2] = v;
            }
            __syncthreads();
            const ushort* wrow = &sm.g.wh[r][kh * 256];
            const float* hp = &sm.g.hs[b][kh * 256];
            float acc = 0.f;
            #pragma unroll 8
            for (int k = 0; k < 256; k += 8) {
                uint4 q = *(const uint4*)(wrow + k);
                float4 ha = *(const float4*)(hp + k);
                float4 hb4 = *(const float4*)(hp + k + 4);
                acc += bf_lo(q.x)*ha.x + bf_hi(q.x)*ha.y + bf_lo(q.y)*ha.z + bf_hi(q.y)*ha.w
                     + bf_lo(q.z)*hb4.x + bf_hi(q.z)*hb4.y + bf_lo(q.w)*hb4.z + bf_hi(q.w)*hb4.w;
            }
            ghp = acc;
        } else {
            int tok = toks[ab * 64 + t];
            if (tid < 256) {
                ull v = __hip_atomic_load((const ull*)H + (size_t)ab * 256 + tid,
                                          __ATOMIC_RELAXED, __HIP_MEMORY_SCOPE_AGENT);
                *(ull*)&sm.a.hb[tid * 2] = v;
            } else if (tid < 768) {
                int k = tid - 256;
                sm.a.ebs[k] = (tok == 0) ? 0.f : embed[(size_t)tok * 512 + k];
            }
            __syncthreads();
            {   // ph partials (whid from L2, bf16)
                int a = tid & 127, kq = tid >> 7;
                const ushort* wr2 = whidbf + (size_t)a * 512 + kq * 64;
                const float* hp = sm.a.hb + kq * 64;
                float p = 0.f;
                #pragma unroll
                for (int k = 0; k < 64; k += 8) {
                    uint4 q = *(const uint4*)(wr2 + k);
                    float4 ha = *(const float4*)(hp + k);
                    float4 hb4 = *(const float4*)(hp + k + 4);
                    p += bf_lo(q.x)*ha.x + bf_hi(q.x)*ha.y + bf_lo(q.y)*ha.z + bf_hi(q.y)*ha.w
                       + bf_lo(q.z)*hb4.x + bf_hi(q.z)*hb4.y + bf_lo(q.w)*hb4.z + bf_hi(q.w)*hb4.w;
                }
                sm.a.php[kq][a] = p;
            }
            __syncthreads();
            if (tid < 128) {
                float p = 0.f;
                #pragma unroll
                for (int kq = 0; kq < 8; kq++) p += sm.a.php[kq][tid];
                sm.a.ph[tid] = p;
            }
            __syncthreads();
            {   // score partials
                int s = tid >> 4, aq = tid & 15;
                float p = 0.f;
                if (s < 49) {
                    const float* pr = proj + (size_t)(ab * 49 + s) * 128 + aq * 8;
                    #pragma unroll
                    for (int a = 0; a < 8; a++)
                        p += ftanh(pr[a] + sm.a.ph[aq * 8 + a]) * wsc[aq * 8 + a];
                }
                sm.a.scp[s][aq] = p;
            }
            __syncthreads();
            if (tid < 64) {
                float v = 0.f;
                #pragma unroll
                for (int q = 0; q < 16; q++) v += sm.a.scp[tid][q];
                if (tid >= 49) v = -1e30f;
                float m = v;
                for (int o = 32; o > 0; o >>= 1) m = fmaxf(m, __shfl_xor(m, o));
                float e = (tid < 49) ? __expf(v - m) : 0.f;
                float su = e;
                for (int o = 32; o > 0; o >>= 1) su += __shfl_xor(su, o);
                sm.a.wsm[tid] = e / su;
            }
            __syncthreads();
            {   // x = embM + sum_s w_s imgEM   (split s over 2 halves)
                int e = tid & 511, sh = tid >> 9;
                float xp = 0.f;
                if (sh == 0) xp = embM[(size_t)(t * 32 + ab) * 512 + e];
                int s0 = sh * 25, s1 = sh ? 49 : 25;
                for (int s = s0; s < s1; s++)
                    xp += sm.a.wsm[s] * imgEM[(size_t)(ab * 49 + s) * 512 + e];
                sm.a.xps[sh][e] = xp;
            }
            __syncthreads();
            if (tid < 512) {
                float x = fmaxf(sm.a.xps[0][tid] + sm.a.xps[1][tid], 0.f);
                float s = x, s2 = x * x;
                for (int o = 32; o > 0; o >>= 1) { s += __shfl_xor(s, o); s2 += __shfl_xor(s2, o); }
                if ((tid & 63) == 0) { sm.a.wred[tid >> 6][0] = s; sm.a.wred[tid >> 6][1] = s2; }
            }
            __syncthreads();
            if (tid == 0) {
                float s = 0.f, s2 = 0.f;
                #pragma unroll
                for (int w = 0; w < 8; w++) { s += sm.a.wred[w][0]; s2 += sm.a.wred[w][1]; }
                float mu = s * (1.f / 512.f);
                float var = s2 * (1.f / 512.f) - mu * mu;
                sm.a.bc[0] = mu; sm.a.bc[1] = rsqrtf(var + 1e-5f);
            }
            __syncthreads();
            if (tid < 512) {
                float x = fmaxf(sm.a.xps[0][tid] + sm.a.xps[1][tid], 0.f);
                float xn = (x - sm.a.bc[0]) * sm.a.bc[1] * lng[tid] + lnb[tid] + sm.a.ebs[tid];
                __hip_atomic_store((unsigned*)&XN[ab * 512 + tid], __float_as_uint(xn),
                                   __ATOMIC_RELAXED, __HIP_MEMORY_SCOPE_AGENT);
            }
        }
        gridbar(BAR, NBLK * (unsigned)(2 * t + 1));

        // ================= phase 2: Wih*xn + cell =================
        if (is_gates) {
            for (int i = tid; i < 8192; i += 1024) {
                int bb = i >> 8, off = i & 255;
                ull v = __hip_atomic_load((const ull*)XN + (size_t)bb * 256 + off,
                                          __ATOMIC_RELAXED, __HIP_MEMORY_SCOPE_AGENT);
                *(ull*)&sm.g.hs[bb][off * 2] = v;
            }
            __syncthreads();
            const ushort* wrow = &sm.g.wi[r][kh * 256];
            const float* xp = &sm.g.hs[b][kh * 256];
            float acc = ghp;
            #pragma unroll 8
            for (int k = 0; k < 256; k += 8) {
                uint4 q = *(const uint4*)(wrow + k);
                float4 xa = *(const float4*)(xp + k);
                float4 xb4 = *(const float4*)(xp + k + 4);
                acc += bf_lo(q.x)*xa.x + bf_hi(q.x)*xa.y + bf_lo(q.y)*xa.z + bf_hi(q.y)*xa.w
                     + bf_lo(q.z)*xb4.x + bf_hi(q.z)*xb4.y + bf_lo(q.w)*xb4.z + bf_hi(q.w)*xb4.w;
            }
            sm.g.red[kh][r][b] = acc;
            __syncthreads();
            if (tid < 128) {
                int jl = tid >> 5, bb = tid & 31;
                float vi = sm.g.red[0][0 + jl][bb]  + sm.g.red[1][0 + jl][bb]  + bs0;
                float vf = sm.g.red[0][4 + jl][bb]  + sm.g.red[1][4 + jl][bb]  + bs1;
                float vg = sm.g.red[0][8 + jl][bb]  + sm.g.red[1][8 + jl][bb]  + bs2;
                float vo = sm.g.red[0][12 + jl][bb] + sm.g.red[1][12 + jl][bb] + bs3;
                float c2 = fsig(vf) * c_reg + fsig(vi) * ftanh(vg);
                float h2 = fsig(vo) * ftanh(c2);
                c_reg = c2;
                int j = g * 4 + jl;
                __hip_atomic_store((unsigned*)&H[bb * 512 + j], __float_as_uint(h2),
                                   __ATOMIC_RELAXED, __HIP_MEMORY_SCOPE_AGENT);
                h2bf[(size_t)(t * 32 + bb) * 512 + j] = f2bf(h2);
            }
        }
        gridbar(BAR, NBLK * (unsigned)(2 * t + 2));
    }
}

// ---------------- deferred head GEMM ----------------
__global__ __launch_bounds__(256) void k_head(const ushort* __restrict__ h2bf,
        const ushort* __restrict__ Wbf, float* __restrict__ out) {
    __shared__ ushort Al[128][72];
    __shared__ ushort Bl[128][72];
    int n0 = blockIdx.x * 128, m0 = blockIdx.y * 128;
    int tid = threadIdx.x, lane = tid & 63, wid = tid >> 6;
    int wm = wid >> 1, wn = wid & 1;
    v4f acc[4][4] = {};
    for (int kt = 0; kt < 512; kt += 64) {
        __syncthreads();
        #pragma unroll
        for (int i = 0; i < 4; i++) {
            int idx = i * 256 + tid;
            int row = idx >> 3, c8 = (idx & 7) * 8;
            *(uint4*)&Al[row][c8] = *(const uint4*)&h2bf[(size_t)(m0 + row) * 512 + kt + c8];
            *(uint4*)&Bl[row][c8] = *(const uint4*)&Wbf[(size_t)(n0 + row) * 512 + kt + c8];
        }
        __syncthreads();
        #pragma unroll
        for (int kk = 0; kk < 2; kk++) {
            v8s a[4], bfr[4];
            int ko = kk * 32 + (lane >> 4) * 8;
            #pragma unroll
            for (int mi = 0; mi < 4; mi++)
                a[mi] = *(const v8s*)&Al[wm * 64 + mi * 16 + (lane & 15)][ko];
            #pragma unroll
            for (int ni = 0; ni < 4; ni++)
                bfr[ni] = *(const v8s*)&Bl[wn * 64 + ni * 16 + (lane & 15)][ko];
            #pragma unroll
            for (int mi = 0; mi < 4; mi++)
                #pragma unroll
                for (int ni = 0; ni < 4; ni++)
                    acc[mi][ni] = __builtin_amdgcn_mfma_f32_16x16x32_bf16(a[mi], bfr[ni], acc[mi][ni], 0, 0, 0);
        }
    }
    int col = lane & 15, rbase = (lane >> 4) * 4;
    #pragma unroll
    for (int mi = 0; mi < 4; mi++)
        #pragma unroll
        for (int ni = 0; ni < 4; ni++)
            #pragma unroll
            for (int r = 0; r < 4; r++) {
                int m = m0 + wm * 64 + mi * 16 + rbase + r;
                int v = n0 + wn * 64 + ni * 16 + col;
                int b = m & 31, t = m >> 5;
                out[((size_t)(b * 64 + t)) * 32000 + v] = acc[mi][ni][r];
            }
}

// ---------------- launch ----------------
extern "C" void kernel_launch(void* const* d_in, const int* in_sizes, int n_in,
                              void* d_out, int out_size, void* d_ws, size_t ws_size,
                              hipStream_t stream) {
    const float* img    = (const float*)d_in[0];
    const int*   toks   = (const int*)d_in[1];
    const float* embed  = (const float*)d_in[2];
    const float* W_ctx  = (const float*)d_in[3];
    const float* W_mix  = (const float*)d_in[4];
    const float* ln_g   = (const float*)d_in[5];
    const float* ln_b   = (const float*)d_in[6];
    const float* W_ih   = (const float*)d_in[7];
    const float* W_hh   = (const float*)d_in[8];
    const float* b_ih   = (const float*)d_in[9];
    const float* b_hh   = (const float*)d_in[10];
    const float* W_head = (const float*)d_in[11];
    const float* W_img  = (const float*)d_in[12];
    const float* W_hid  = (const float*)d_in[13];
    const float* w_sc   = (const float*)d_in[14];
    const float* W_h0   = (const float*)d_in[15];
    const float* b_h0   = (const float*)d_in[16];
    const float* W_c0   = (const float*)d_in[17];
    const float* b_c0   = (const float*)d_in[18];

    float* out = (float*)d_out;
    float* ws  = (float*)d_ws;
    ushort* Wbf    = (ushort*)(ws + WS_WBF);
    ushort* h2bf   = (ushort*)(ws + WS_H2BF);
    float*  imgEM  = ws + WS_IMGEM;
    float*  proj   = ws + WS_PROJ;
    float*  embM   = ws + WS_EMBM;
    ushort* whhbf  = (ushort*)(ws + WS_WHHBF);
    ushort* wihbf  = (ushort*)(ws + WS_WIHBF);
    ushort* whidbf = (ushort*)(ws + WS_WHIDBF);
    float*  H      = ws + WS_H;
    float*  XN     = ws + WS_XN;
    float*  C      = ws + WS_C;
    unsigned* bar  = (unsigned*)(ws + WS_BAR);
    float*  g      = ws + WS_G;
    // prep scratch (inside Wbf slot)
    ushort* imgbf   = (ushort*)(ws + PS_IMGBF);
    ushort* wctxbf  = (ushort*)(ws + PS_WCTXBF);
    ushort* wimgbf  = (ushort*)(ws + PS_WIMGBF);
    ushort* wmixRbf = (ushort*)(ws + PS_WMIXRBF);
    float*  imgE    = ws + PS_IMGE;
    ushort* imgEbf  = (ushort*)(ws + PS_IMGEBF);
    ushort* embG    = (ushort*)(ws + PS_EMBG);
    ushort* wmixLbf = (ushort*)(ws + PS_WMIXLBF);

    // prep A: casts into scratch
    k_castpad<<<1664, 256, 0, stream>>>(img,   imgbf,   1568, 1664, 2048, 2048, 0);
    k_castpad<<<512,  256, 0, stream>>>(W_ctx, wctxbf,  512,  512,  2048, 2048, 0);
    k_castpad<<<128,  256, 0, stream>>>(W_img, wimgbf,  128,  128,  2048, 2048, 0);
    k_castpad<<<128,  256, 0, stream>>>(W_mix, wmixRbf, 512,  512,  512,  1024, 512);
    k_castpad<<<128,  256, 0, stream>>>(W_mix, wmixLbf, 512,  512,  512,  1024, 0);
    k_embg<<<2048, 128, 0, stream>>>(toks, embed, embG);
    // prep B: MFMA GEMMs
    k_gemm<<<dim3(4, 13), 256, 0, stream>>>(imgbf, wctxbf, imgE, 512, 2048);
    k_gemm<<<dim3(1, 13), 256, 0, stream>>>(imgbf, wimgbf, proj, 128, 2048);
    k_gemm<<<dim3(4, 16), 256, 0, stream>>>(embG, wmixLbf, embM, 512, 512);
    k_castpad<<<416, 256, 0, stream>>>(imgE, imgEbf, 1664, 1664, 512, 512, 0);
    k_gemm<<<dim3(4, 13), 256, 0, stream>>>(imgEbf, wmixRbf, imgEM, 512, 512);
    // prep C: persistent bf16 weights
    k_castpad<<<512, 256, 0, stream>>>(W_hh,  whhbf,  2048, 2048, 512, 512, 0);
    k_castpad<<<512, 256, 0, stream>>>(W_ih,  wihbf,  2048, 2048, 512, 512, 0);
    k_castpad<<<32,  256, 0, stream>>>(W_hid, whidbf, 128,  128,  512, 512, 0);
    // prep D: head weights (overwrites scratch region)
    k_castpad<<<8000, 256, 0, stream>>>(W_head, Wbf, 32000, 32000, 512, 512, 0);
    // prep E: init state
    k_gmean<<<32, 256, 0, stream>>>(img, g);
    k_h0c0<<<64, 256, 0, stream>>>(g, W_h0, b_h0, W_c0, b_c0, H, C);
    hipMemsetAsync(bar, 0, 256, stream);

    // recurrence: 128 gates blocks (LDS-pinned weights) + 32 attn blocks
    k_persist<<<NBLK, 1024, 0, stream>>>(toks, embed, ln_g, ln_b, b_ih, b_hh, w_sc,
                                         whidbf, whhbf, wihbf, proj, imgEM, embM,
                                         H, C, XN, bar, h2bf);

    // deferred batched head GEMM
    k_head<<<dim3(250, 16), 256, 0, stream>>>(h2bf, Wbf, out);
}

// Round 7
// 1764.161 us; speedup vs baseline: 14.7527x; 1.1684x over previous
//
#include <hip/hip_runtime.h>

#define NV 32000
#define NT 64
#define NBLK 160u

typedef unsigned long long ull;
typedef unsigned short ushort;
typedef __attribute__((ext_vector_type(8))) short v8s;
typedef __attribute__((ext_vector_type(4))) float v4f;

// persistent ws layout (float offsets; ushort regions = count/2 floats)
#define WS_WBF     0          // ushort [32000][512]           -> 8192000
#define WS_H2BF    8192000    // ushort [2048][512]  (524288)  -> 8716288
#define WS_IMGEM   8716288    // f32 [1664][512]     (851968)  -> 9568256
#define WS_PROJ    9568256    // f32 [1664][128]     (212992)  -> 9781248
#define WS_EMBM    9781248    // f32 [2048][512]     (1048576) -> 10829824
#define WS_WHHBF   10829824   // ushort [2048][512]  (524288)  -> 11354112
#define WS_WIHBF   11354112   // ushort [2048][512]  (524288)  -> 11878400
#define WS_WHIDBF  11878400   // ushort [128][512]   (32768)   -> 11911168
#define WS_H       11911168   // f32 [32][512]       (16384)   -> 11927552
#define WS_XN      11927552   // f32 [32][512]       (16384)   -> 11943936
#define WS_C       11943936   // f32 [32][512]       (16384)   -> 11960320
#define WS_BAR     11960320   // barrier: go + 159 slots, 64B-padded (2560) -> 11962880
#define WS_G       11962880   // f32 [32][2048]      (65536)   -> 12028416
// prep scratch (inside Wbf slot [0,8192000); dead before W_head cast)
#define PS_IMGBF   0          // ushort [1664][2048] (1703936) -> 1703936
#define PS_WCTXBF  1703936    // ushort [512][2048]  (524288)  -> 2228224
#define PS_WIMGBF  2228224    // ushort [128][2048]  (131072)  -> 2359296
#define PS_WMIXRBF 2359296    // ushort [512][512]   (131072)  -> 2490368
#define PS_IMGE    2490368    // f32 [1664][512]     (851968)  -> 3342336
#define PS_IMGEBF  3342336    // ushort [1664][512]  (425984)  -> 3768320
#define PS_EMBG    3768320    // ushort [2048][512]  (524288)  -> 4292608
#define PS_WMIXLBF 4292608    // ushort [512][512]   (131072)  -> 4423680

__device__ __forceinline__ float fsig(float x) {
    x = fminf(fmaxf(x, -30.f), 30.f);
    return 1.f / (1.f + __expf(-x));
}
__device__ __forceinline__ float ftanh(float x) {
    x = fminf(fmaxf(x, -15.f), 15.f);
    float e = __expf(2.f * x);
    return (e - 1.f) / (e + 1.f);
}
__device__ __forceinline__ unsigned short f2bf(float f) {
    union { float f; unsigned int u; } v; v.f = f;
    unsigned int u = v.u;
    return (unsigned short)((u + 0x7FFFu + ((u >> 16) & 1u)) >> 16);
}
__device__ __forceinline__ float bf_lo(unsigned u) { return __uint_as_float(u << 16); }
__device__ __forceinline__ float bf_hi(unsigned u) { return __uint_as_float(u & 0xffff0000u); }

// ---------------- prep kernels ----------------

__global__ __launch_bounds__(256) void k_castpad(const float* __restrict__ in,
        ushort* __restrict__ out, int R, int Rpad, int K, int ldi, int off) {
    size_t i = ((size_t)blockIdx.x * 256 + threadIdx.x) * 8;
    if (i >= (size_t)Rpad * K) return;
    int r = (int)(i / K), k = (int)(i % K);
    uint4 o = {0, 0, 0, 0};
    if (r < R) {
        const float* p = in + (size_t)r * ldi + off + k;
        float4 a = *(const float4*)(p);
        float4 b = *(const float4*)(p + 4);
        o.x = (unsigned)f2bf(a.x) | ((unsigned)f2bf(a.y) << 16);
        o.y = (unsigned)f2bf(a.z) | ((unsigned)f2bf(a.w) << 16);
        o.z = (unsigned)f2bf(b.x) | ((unsigned)f2bf(b.y) << 16);
        o.w = (unsigned)f2bf(b.z) | ((unsigned)f2bf(b.w) << 16);
    }
    *(uint4*)(out + i) = o;
}

// gather token embeddings: embG[(t*32+b)][k] = bf16(embed[tok]*(tok!=0))
__global__ __launch_bounds__(128) void k_embg(const int* __restrict__ toks,
        const float* __restrict__ embed, ushort* __restrict__ embG) {
    int row = blockIdx.x;
    int t = row >> 5, b = row & 31;
    int tok = toks[b * 64 + t];
    int e = threadIdx.x * 4;
    uint2 o = {0, 0};
    if (tok != 0) {
        float4 a = *(const float4*)&embed[(size_t)tok * 512 + e];
        o.x = (unsigned)f2bf(a.x) | ((unsigned)f2bf(a.y) << 16);
        o.y = (unsigned)f2bf(a.z) | ((unsigned)f2bf(a.w) << 16);
    }
    *(uint2*)&embG[(size_t)row * 512 + e] = o;
}

// C[m][n] = sum_k A[m][k]*B[n][k]
__global__ __launch_bounds__(256) void k_gemm(const ushort* __restrict__ A,
        const ushort* __restrict__ B, float* __restrict__ C, int N, int K) {
    __shared__ ushort Al[128][72];
    __shared__ ushort Bl[128][72];
    int n0 = blockIdx.x * 128, m0 = blockIdx.y * 128;
    int tid = threadIdx.x, lane = tid & 63, wid = tid >> 6;
    int wm = wid >> 1, wn = wid & 1;
    v4f acc[4][4] = {};
    for (int kt = 0; kt < K; kt += 64) {
        __syncthreads();
        #pragma unroll
        for (int i = 0; i < 4; i++) {
            int idx = i * 256 + tid;
            int row = idx >> 3, c8 = (idx & 7) * 8;
            *(uint4*)&Al[row][c8] = *(const uint4*)&A[(size_t)(m0 + row) * K + kt + c8];
            *(uint4*)&Bl[row][c8] = *(const uint4*)&B[(size_t)(n0 + row) * K + kt + c8];
        }
        __syncthreads();
        #pragma unroll
        for (int kk = 0; kk < 2; kk++) {
            v8s a[4], bfr[4];
            int ko = kk * 32 + (lane >> 4) * 8;
            #pragma unroll
            for (int mi = 0; mi < 4; mi++)
                a[mi] = *(const v8s*)&Al[wm * 64 + mi * 16 + (lane & 15)][ko];
            #pragma unroll
            for (int ni = 0; ni < 4; ni++)
                bfr[ni] = *(const v8s*)&Bl[wn * 64 + ni * 16 + (lane & 15)][ko];
            #pragma unroll
            for (int mi = 0; mi < 4; mi++)
                #pragma unroll
                for (int ni = 0; ni < 4; ni++)
                    acc[mi][ni] = __builtin_amdgcn_mfma_f32_16x16x32_bf16(a[mi], bfr[ni], acc[mi][ni], 0, 0, 0);
        }
    }
    int col = lane & 15, rbase = (lane >> 4) * 4;
    #pragma unroll
    for (int mi = 0; mi < 4; mi++)
        #pragma unroll
        for (int ni = 0; ni < 4; ni++)
            #pragma unroll
            for (int r = 0; r < 4; r++) {
                int m = m0 + wm * 64 + mi * 16 + rbase + r;
                int v = n0 + wn * 64 + ni * 16 + col;
                C[(size_t)m * N + v] = acc[mi][ni][r];
            }
}

__global__ __launch_bounds__(256) void k_gmean(const float* __restrict__ img,
                                               float* __restrict__ g) {
    int b = blockIdx.x;
    for (int d = threadIdx.x; d < 2048; d += 256) {
        float s = 0.f;
        for (int ss = 0; ss < 49; ss++) s += img[((size_t)(b * 49 + ss)) * 2048 + d];
        g[b * 2048 + d] = s * (1.f / 49.f);
    }
}

__global__ __launch_bounds__(256) void k_h0c0(const float* __restrict__ g,
        const float* __restrict__ Wh0, const float* __restrict__ bh0,
        const float* __restrict__ Wc0, const float* __restrict__ bc0,
        float* __restrict__ h0, float* __restrict__ c0) {
    int b = blockIdx.x >> 1, m = blockIdx.x & 1;
    __shared__ float gs[2048];
    for (int d = threadIdx.x; d < 2048; d += 256) gs[d] = g[b * 2048 + d];
    __syncthreads();
    const float* W = m ? Wc0 : Wh0;
    const float* bb = m ? bc0 : bh0;
    float* out = m ? c0 : h0;
    for (int r = threadIdx.x; r < 512; r += 256) {
        float acc = 0.f;
        const float* wr = W + (size_t)r * 2048;
        for (int d = 0; d < 2048; d += 4) {
            float4 w = *(const float4*)(wr + d);
            acc += w.x * gs[d] + w.y * gs[d + 1] + w.z * gs[d + 2] + w.w * gs[d + 3];
        }
        out[b * 512 + r] = ftanh(acc + bb[r]) * 0.5f;
    }
}

// ---------------- persistent recurrence ----------------
// Weights pinned in LDS (gates) or L2-resident (attn path).
// Cross-block data only through relaxed agent-scope atomics. No fences.
//
// Flat store/poll barrier: each block STOREs its epoch into a private
// 64B-padded slot (parallel at LLC, no RMW serialization); block 0's wave 0
// polls all slots then stores a go-epoch; everyone else spins on go only.
// __syncthreads before the arrival store drains vmcnt(0), so an observed
// slot implies that block's agent-scope data stores are LLC-visible.

__device__ __forceinline__ void gridbar(unsigned* bar, unsigned epoch) {
    __syncthreads();
    if (blockIdx.x == 0) {
        if (threadIdx.x < 64) {
            int alldone;
            do {
                bool mine = true;
                for (int i = threadIdx.x; i < (int)NBLK - 1; i += 64) {
                    unsigned v = __hip_atomic_load(bar + 16 + i * 16,
                                   __ATOMIC_RELAXED, __HIP_MEMORY_SCOPE_AGENT);
                    if (v < epoch) mine = false;
                }
                alldone = __all(mine ? 1 : 0);
                if (!alldone) __builtin_amdgcn_s_sleep(1);
            } while (!alldone);
            if (threadIdx.x == 0)
                __hip_atomic_store(bar, epoch, __ATOMIC_RELAXED, __HIP_MEMORY_SCOPE_AGENT);
        }
    } else {
        if (threadIdx.x == 0) {
            __hip_atomic_store(bar + 16 + (blockIdx.x - 1) * 16, epoch,
                               __ATOMIC_RELAXED, __HIP_MEMORY_SCOPE_AGENT);
            while (__hip_atomic_load(bar, __ATOMIC_RELAXED, __HIP_MEMORY_SCOPE_AGENT) < epoch)
                __builtin_amdgcn_s_sleep(1);
        }
    }
    __syncthreads();
}

union SMem {
    struct {                       // gates role (blocks 0..127)
        ushort wh[16][520];        // W_hh rows, bf16, padded
        ushort wi[16][520];        // W_ih rows
        float hs[32][516];         // staged H (phase1) / XN (phase2)
        float red[2][16][32];      // kh partials
    } g;                           // 103424 B
    struct {                       // attention role (blocks 128..159)
        float hb[512];
        float ebs[512];
        float php[8][128];
        float ph[128];
        float scp[64][16];
        float wsm[64];
        float xps[2][512];
        float wred[8][2];
        float bc[2];
    } a;
};

__global__ __launch_bounds__(1024, 1) void k_persist(
        const int* __restrict__ toks, const float* __restrict__ embed,
        const float* __restrict__ lng, const float* __restrict__ lnb,
        const float* __restrict__ bih, const float* __restrict__ bhh,
        const float* __restrict__ wsc, const ushort* __restrict__ whidbf,
        const ushort* __restrict__ whhbf, const ushort* __restrict__ wihbf,
        const float* __restrict__ proj, const float* __restrict__ imgEM,
        const float* __restrict__ embM, float* __restrict__ H,
        const float* __restrict__ C0, float* __restrict__ XN,
        unsigned* __restrict__ BAR, ushort* __restrict__ h2bf) {
    __shared__ SMem sm;
    int blk = blockIdx.x, tid = threadIdx.x;
    bool is_gates = (blk < 128);
    int g = blk;                       // gates: j-chunk [g*4, g*4+4)
    int r = (tid >> 5) & 15, b = tid & 31, kh = tid >> 9;
    int ab = blk - 128;                // attn: batch index
    float c_reg = 0.f, bs0 = 0.f, bs1 = 0.f, bs2 = 0.f, bs3 = 0.f;
    float ghp = 0.f;

    if (is_gates) {
        // pin weight slice in LDS (once)
        int wr_ = tid >> 6, c8 = (tid & 63) * 8;      // 16 rows x 8 uint4
        int gate = wr_ >> 2, jj = wr_ & 3;
        size_t R = (size_t)(gate * 512 + g * 4 + jj) * 512 + c8;
        *(uint4*)&sm.g.wh[wr_][c8] = *(const uint4*)&whhbf[R];
        *(uint4*)&sm.g.wi[wr_][c8] = *(const uint4*)&wihbf[R];
        if (tid < 128) {
            int jl = tid >> 5, bb = tid & 31;
            int j = g * 4 + jl;
            c_reg = C0[bb * 512 + j];
            bs0 = bih[j] + bhh[j];
            bs1 = bih[512 + j] + bhh[512 + j];
            bs2 = bih[1024 + j] + bhh[1024 + j];
            bs3 = bih[1536 + j] + bhh[1536 + j];
        }
    }
    __syncthreads();

    for (int t = 0; t < NT; t++) {
        // ================= phase 1: Whh*h | attention+LN =================
        if (is_gates) {
            for (int i = tid; i < 8192; i += 1024) {
                int bb = i >> 8, off = i & 255;
                ull v = __hip_atomic_load((const ull*)H + (size_t)bb * 256 + off,
                                          __ATOMIC_RELAXED, __HIP_MEMORY_SCOPE_AGENT);
                *(ull*)&sm.g.hs[bb][off * 2] = v;
            }
            __syncthreads();
            const ushort* wrow = &sm.g.wh[r][kh * 256];
            const float* hp = &sm.g.hs[b][kh * 256];
            float acc = 0.f;
            #pragma unroll 8
            for (int k = 0; k < 256; k += 8) {
                uint4 q = *(const uint4*)(wrow + k);
                float4 ha = *(const float4*)(hp + k);
                float4 hb4 = *(const float4*)(hp + k + 4);
                acc += bf_lo(q.x)*ha.x + bf_hi(q.x)*ha.y + bf_lo(q.y)*ha.z + bf_hi(q.y)*ha.w
                     + bf_lo(q.z)*hb4.x + bf_hi(q.z)*hb4.y + bf_lo(q.w)*hb4.z + bf_hi(q.w)*hb4.w;
            }
            ghp = acc;
        } else {
            int tok = toks[ab * 64 + t];
            if (tid < 256) {
                ull v = __hip_atomic_load((const ull*)H + (size_t)ab * 256 + tid,
                                          __ATOMIC_RELAXED, __HIP_MEMORY_SCOPE_AGENT);
                *(ull*)&sm.a.hb[tid * 2] = v;
            } else if (tid < 768) {
                int k = tid - 256;
                sm.a.ebs[k] = (tok == 0) ? 0.f : embed[(size_t)tok * 512 + k];
            }
            __syncthreads();
            {   // ph partials (whid from L2, bf16)
                int a = tid & 127, kq = tid >> 7;
                const ushort* wr2 = whidbf + (size_t)a * 512 + kq * 64;
                const float* hp = sm.a.hb + kq * 64;
                float p = 0.f;
                #pragma unroll
                for (int k = 0; k < 64; k += 8) {
                    uint4 q = *(const uint4*)(wr2 + k);
                    float4 ha = *(const float4*)(hp + k);
                    float4 hb4 = *(const float4*)(hp + k + 4);
                    p += bf_lo(q.x)*ha.x + bf_hi(q.x)*ha.y + bf_lo(q.y)*ha.z + bf_hi(q.y)*ha.w
                       + bf_lo(q.z)*hb4.x + bf_hi(q.z)*hb4.y + bf_lo(q.w)*hb4.z + bf_hi(q.w)*hb4.w;
                }
                sm.a.php[kq][a] = p;
            }
            __syncthreads();
            if (tid < 128) {
                float p = 0.f;
                #pragma unroll
                for (int kq = 0; kq < 8; kq++) p += sm.a.php[kq][tid];
                sm.a.ph[tid] = p;
            }
            __syncthreads();
            {   // score partials
                int s = tid >> 4, aq = tid & 15;
                float p = 0.f;
                if (s < 49) {
                    const float* pr = proj + (size_t)(ab * 49 + s) * 128 + aq * 8;
                    #pragma unroll
                    for (int a = 0; a < 8; a++)
                        p += ftanh(pr[a] + sm.a.ph[aq * 8 + a]) * wsc[aq * 8 + a];
                }
                sm.a.scp[s][aq] = p;
            }
            __syncthreads();
            if (tid < 64) {
                float v = 0.f;
                #pragma unroll
                for (int q = 0; q < 16; q++) v += sm.a.scp[tid][q];
                if (tid >= 49) v = -1e30f;
                float m = v;
                for (int o = 32; o > 0; o >>= 1) m = fmaxf(m, __shfl_xor(m, o));
                float e = (tid < 49) ? __expf(v - m) : 0.f;
                float su = e;
                for (int o = 32; o > 0; o >>= 1) su += __shfl_xor(su, o);
                sm.a.wsm[tid] = e / su;
            }
            __syncthreads();
            {   // x = embM + sum_s w_s imgEM   (split s over 2 halves)
                int e = tid & 511, sh = tid >> 9;
                float xp = 0.f;
                if (sh == 0) xp = embM[(size_t)(t * 32 + ab) * 512 + e];
                int s0 = sh * 25, s1 = sh ? 49 : 25;
                for (int s = s0; s < s1; s++)
                    xp += sm.a.wsm[s] * imgEM[(size_t)(ab * 49 + s) * 512 + e];
                sm.a.xps[sh][e] = xp;
            }
            __syncthreads();
            if (tid < 512) {
                float x = fmaxf(sm.a.xps[0][tid] + sm.a.xps[1][tid], 0.f);
                float s = x, s2 = x * x;
                for (int o = 32; o > 0; o >>= 1) { s += __shfl_xor(s, o); s2 += __shfl_xor(s2, o); }
                if ((tid & 63) == 0) { sm.a.wred[tid >> 6][0] = s; sm.a.wred[tid >> 6][1] = s2; }
            }
            __syncthreads();
            if (tid == 0) {
                float s = 0.f, s2 = 0.f;
                #pragma unroll
                for (int w = 0; w < 8; w++) { s += sm.a.wred[w][0]; s2 += sm.a.wred[w][1]; }
                float mu = s * (1.f / 512.f);
                float var = s2 * (1.f / 512.f) - mu * mu;
                sm.a.bc[0] = mu; sm.a.bc[1] = rsqrtf(var + 1e-5f);
            }
            __syncthreads();
            if (tid < 512) {
                float x = fmaxf(sm.a.xps[0][tid] + sm.a.xps[1][tid], 0.f);
                float xn = (x - sm.a.bc[0]) * sm.a.bc[1] * lng[tid] + lnb[tid] + sm.a.ebs[tid];
                __hip_atomic_store((unsigned*)&XN[ab * 512 + tid], __float_as_uint(xn),
                                   __ATOMIC_RELAXED, __HIP_MEMORY_SCOPE_AGENT);
            }
        }
        gridbar(BAR, (unsigned)(2 * t + 1));

        // ================= phase 2: Wih*xn + cell =================
        if (is_gates) {
            for (int i = tid; i < 8192; i += 1024) {
                int bb = i >> 8, off = i & 255;
                ull v = __hip_atomic_load((const ull*)XN + (size_t)bb * 256 + off,
                                          __ATOMIC_RELAXED, __HIP_MEMORY_SCOPE_AGENT);
                *(ull*)&sm.g.hs[bb][off * 2] = v;
            }
            __syncthreads();
            const ushort* wrow = &sm.g.wi[r][kh * 256];
            const float* xp = &sm.g.hs[b][kh * 256];
            float acc = ghp;
            #pragma unroll 8
            for (int k = 0; k < 256; k += 8) {
                uint4 q = *(const uint4*)(wrow + k);
                float4 xa = *(const float4*)(xp + k);
                float4 xb4 = *(const float4*)(xp + k + 4);
                acc += bf_lo(q.x)*xa.x + bf_hi(q.x)*xa.y + bf_lo(q.y)*xa.z + bf_hi(q.y)*xa.w
                     + bf_lo(q.z)*xb4.x + bf_hi(q.z)*xb4.y + bf_lo(q.w)*xb4.z + bf_hi(q.w)*xb4.w;
            }
            sm.g.red[kh][r][b] = acc;
            __syncthreads();
            if (tid < 128) {
                int jl = tid >> 5, bb = tid & 31;
                float vi = sm.g.red[0][0 + jl][bb]  + sm.g.red[1][0 + jl][bb]  + bs0;
                float vf = sm.g.red[0][4 + jl][bb]  + sm.g.red[1][4 + jl][bb]  + bs1;
                float vg = sm.g.red[0][8 + jl][bb]  + sm.g.red[1][8 + jl][bb]  + bs2;
                float vo = sm.g.red[0][12 + jl][bb] + sm.g.red[1][12 + jl][bb] + bs3;
                float c2 = fsig(vf) * c_reg + fsig(vi) * ftanh(vg);
                float h2 = fsig(vo) * ftanh(c2);
                c_reg = c2;
                int j = g * 4 + jl;
                __hip_atomic_store((unsigned*)&H[bb * 512 + j], __float_as_uint(h2),
                                   __ATOMIC_RELAXED, __HIP_MEMORY_SCOPE_AGENT);
                h2bf[(size_t)(t * 32 + bb) * 512 + j] = f2bf(h2);
            }
        }
        gridbar(BAR, (unsigned)(2 * t + 2));
    }
}

// ---------------- deferred head GEMM ----------------
__global__ __launch_bounds__(256) void k_head(const ushort* __restrict__ h2bf,
        const ushort* __restrict__ Wbf, float* __restrict__ out) {
    __shared__ ushort Al[128][72];
    __shared__ ushort Bl[128][72];
    int n0 = blockIdx.x * 128, m0 = blockIdx.y * 128;
    int tid = threadIdx.x, lane = tid & 63, wid = tid >> 6;
    int wm = wid >> 1, wn = wid & 1;
    v4f acc[4][4] = {};
    for (int kt = 0; kt < 512; kt += 64) {
        __syncthreads();
        #pragma unroll
        for (int i = 0; i < 4; i++) {
            int idx = i * 256 + tid;
            int row = idx >> 3, c8 = (idx & 7) * 8;
            *(uint4*)&Al[row][c8] = *(const uint4*)&h2bf[(size_t)(m0 + row) * 512 + kt + c8];
            *(uint4*)&Bl[row][c8] = *(const uint4*)&Wbf[(size_t)(n0 + row) * 512 + kt + c8];
        }
        __syncthreads();
        #pragma unroll
        for (int kk = 0; kk < 2; kk++) {
            v8s a[4], bfr[4];
            int ko = kk * 32 + (lane >> 4) * 8;
            #pragma unroll
            for (int mi = 0; mi < 4; mi++)
                a[mi] = *(const v8s*)&Al[wm * 64 + mi * 16 + (lane & 15)][ko];
            #pragma unroll
            for (int ni = 0; ni < 4; ni++)
                bfr[ni] = *(const v8s*)&Bl[wn * 64 + ni * 16 + (lane & 15)][ko];
            #pragma unroll
            for (int mi = 0; mi < 4; mi++)
                #pragma unroll
                for (int ni = 0; ni < 4; ni++)
                    acc[mi][ni] = __builtin_amdgcn_mfma_f32_16x16x32_bf16(a[mi], bfr[ni], acc[mi][ni], 0, 0, 0);
        }
    }
    int col = lane & 15, rbase = (lane >> 4) * 4;
    #pragma unroll
    for (int mi = 0; mi < 4; mi++)
        #pragma unroll
        for (int ni = 0; ni < 4; ni++)
            #pragma unroll
            for (int r = 0; r < 4; r++) {
                int m = m0 + wm * 64 + mi * 16 + rbase + r;
                int v = n0 + wn * 64 + ni * 16 + col;
                int b = m & 31, t = m >> 5;
                out[((size_t)(b * 64 + t)) * 32000 + v] = acc[mi][ni][r];
            }
}

// ---------------- launch ----------------
extern "C" void kernel_launch(void* const* d_in, const int* in_sizes, int n_in,
                              void* d_out, int out_size, void* d_ws, size_t ws_size,
                              hipStream_t stream) {
    const float* img    = (const float*)d_in[0];
    const int*   toks   = (const int*)d_in[1];
    const float* embed  = (const float*)d_in[2];
    const float* W_ctx  = (const float*)d_in[3];
    const float* W_mix  = (const float*)d_in[4];
    const float* ln_g   = (const float*)d_in[5];
    const float* ln_b   = (const float*)d_in[6];
    const float* W_ih   = (const float*)d_in[7];
    const float* W_hh   = (const float*)d_in[8];
    const float* b_ih   = (const float*)d_in[9];
    const float* b_hh   = (const float*)d_in[10];
    const float* W_head = (const float*)d_in[11];
    const float* W_img  = (const float*)d_in[12];
    const float* W_hid  = (const float*)d_in[13];
    const float* w_sc   = (const float*)d_in[14];
    const float* W_h0   = (const float*)d_in[15];
    const float* b_h0   = (const float*)d_in[16];
    const float* W_c0   = (const float*)d_in[17];
    const float* b_c0   = (const float*)d_in[18];

    float* out = (float*)d_out;
    float* ws  = (float*)d_ws;
    ushort* Wbf    = (ushort*)(ws + WS_WBF);
    ushort* h2bf   = (ushort*)(ws + WS_H2BF);
    float*  imgEM  = ws + WS_IMGEM;
    float*  proj   = ws + WS_PROJ;
    float*  embM   = ws + WS_EMBM;
    ushort* whhbf  = (ushort*)(ws + WS_WHHBF);
    ushort* wihbf  = (ushort*)(ws + WS_WIHBF);
    ushort* whidbf = (ushort*)(ws + WS_WHIDBF);
    float*  H      = ws + WS_H;
    float*  XN     = ws + WS_XN;
    float*  C      = ws + WS_C;
    unsigned* bar  = (unsigned*)(ws + WS_BAR);
    float*  g      = ws + WS_G;
    // prep scratch (inside Wbf slot)
    ushort* imgbf   = (ushort*)(ws + PS_IMGBF);
    ushort* wctxbf  = (ushort*)(ws + PS_WCTXBF);
    ushort* wimgbf  = (ushort*)(ws + PS_WIMGBF);
    ushort* wmixRbf = (ushort*)(ws + PS_WMIXRBF);
    float*  imgE    = ws + PS_IMGE;
    ushort* imgEbf  = (ushort*)(ws + PS_IMGEBF);
    ushort* embG    = (ushort*)(ws + PS_EMBG);
    ushort* wmixLbf = (ushort*)(ws + PS_WMIXLBF);

    // prep A: casts into scratch
    k_castpad<<<1664, 256, 0, stream>>>(img,   imgbf,   1568, 1664, 2048, 2048, 0);
    k_castpad<<<512,  256, 0, stream>>>(W_ctx, wctxbf,  512,  512,  2048, 2048, 0);
    k_castpad<<<128,  256, 0, stream>>>(W_img, wimgbf,  128,  128,  2048, 2048, 0);
    k_castpad<<<128,  256, 0, stream>>>(W_mix, wmixRbf, 512,  512,  512,  1024, 512);
    k_castpad<<<128,  256, 0, stream>>>(W_mix, wmixLbf, 512,  512,  512,  1024, 0);
    k_embg<<<2048, 128, 0, stream>>>(toks, embed, embG);
    // prep B: MFMA GEMMs
    k_gemm<<<dim3(4, 13), 256, 0, stream>>>(imgbf, wctxbf, imgE, 512, 2048);
    k_gemm<<<dim3(1, 13), 256, 0, stream>>>(imgbf, wimgbf, proj, 128, 2048);
    k_gemm<<<dim3(4, 16), 256, 0, stream>>>(embG, wmixLbf, embM, 512, 512);
    k_castpad<<<416, 256, 0, stream>>>(imgE, imgEbf, 1664, 1664, 512, 512, 0);
    k_gemm<<<dim3(4, 13), 256, 0, stream>>>(imgEbf, wmixRbf, imgEM, 512, 512);
    // prep C: persistent bf16 weights
    k_castpad<<<512, 256, 0, stream>>>(W_hh,  whhbf,  2048, 2048, 512, 512, 0);
    k_castpad<<<512, 256, 0, stream>>>(W_ih,  wihbf,  2048, 2048, 512, 512, 0);
    k_castpad<<<32,  256, 0, stream>>>(W_hid, whidbf, 128,  128,  512, 512, 0);
    // prep D: head weights (overwrites scratch region)
    k_castpad<<<8000, 256, 0, stream>>>(W_head, Wbf, 32000, 32000, 512, 512, 0);
    // prep E: init state
    k_gmean<<<32, 256, 0, stream>>>(img, g);
    k_h0c0<<<64, 256, 0, stream>>>(g, W_h0, b_h0, W_c0, b_c0, H, C);
    hipMemsetAsync(bar, 0, 10496, stream);   // go flag + 159 slots (64B-padded)

    // recurrence: 128 gates blocks (LDS-pinned weights) + 32 attn blocks
    k_persist<<<NBLK, 1024, 0, stream>>>(toks, embed, ln_g, ln_b, b_ih, b_hh, w_sc,
                                         whidbf, whhbf, wihbf, proj, imgEM, embM,
                                         H, C, XN, bar, h2bf);

    // deferred batched head GEMM
    k_head<<<dim3(250, 16), 256, 0, stream>>>(h2bf, Wbf, out);
}

// Round 8
// 1163.330 us; speedup vs baseline: 22.3721x; 1.5165x over previous
//
#include <hip/hip_runtime.h>

#define NV 32000
#define NT 64
#define NBLK 160u

typedef unsigned long long ull;
typedef unsigned short ushort;
typedef __attribute__((ext_vector_type(8))) short v8s;
typedef __attribute__((ext_vector_type(4))) float v4f;

// persistent ws layout (float offsets; ushort regions = count/2 floats)
#define WS_WBF     0          // ushort [32000][512]           -> 8192000
#define WS_H2BF    8192000    // ushort [2048][512]  (524288)  -> 8716288
#define WS_IMGEM   8716288    // f32 [1664][512]     (851968)  -> 9568256
#define WS_PROJ    9568256    // f32 [1664][128]     (212992)  -> 9781248
#define WS_EMBM    9781248    // f32 [2048][512]     (1048576) -> 10829824
#define WS_WHHBF   10829824   // ushort [2048][512]  (524288)  -> 11354112
#define WS_WIHBF   11354112   // ushort [2048][512]  (524288)  -> 11878400
#define WS_WHIDBF  11878400   // ushort [128][512]   (32768)   -> 11911168
#define WS_H       11911168   // f32 [2][32][512]    (32768)   -> 11943936
#define WS_XN      11943936   // f32 [32][512]       (16384)   -> 11960320
#define WS_C       11960320   // f32 [32][512]       (16384)   -> 11976704
#define WS_FLAGS   11976704   // 160 slots x 16 u32  (2560)    -> 11979264
#define WS_G       11979264   // f32 [32][2048]      (65536)   -> 12044800
// prep scratch (inside Wbf slot [0,8192000); dead before W_head cast)
#define PS_IMGBF   0          // ushort [1664][2048] (1703936) -> 1703936
#define PS_WCTXBF  1703936    // ushort [512][2048]  (524288)  -> 2228224
#define PS_WIMGBF  2228224    // ushort [128][2048]  (131072)  -> 2359296
#define PS_WMIXRBF 2359296    // ushort [512][512]   (131072)  -> 2490368
#define PS_IMGE    2490368    // f32 [1664][512]     (851968)  -> 3342336
#define PS_IMGEBF  3342336    // ushort [1664][512]  (425984)  -> 3768320
#define PS_EMBG    3768320    // ushort [2048][512]  (524288)  -> 4292608
#define PS_WMIXLBF 4292608    // ushort [512][512]   (131072)  -> 4423680

__device__ __forceinline__ float fsig(float x) {
    x = fminf(fmaxf(x, -30.f), 30.f);
    return 1.f / (1.f + __expf(-x));
}
__device__ __forceinline__ float ftanh(float x) {
    x = fminf(fmaxf(x, -15.f), 15.f);
    float e = __expf(2.f * x);
    return (e - 1.f) / (e + 1.f);
}
__device__ __forceinline__ unsigned short f2bf(float f) {
    union { float f; unsigned int u; } v; v.f = f;
    unsigned int u = v.u;
    return (unsigned short)((u + 0x7FFFu + ((u >> 16) & 1u)) >> 16);
}
__device__ __forceinline__ float bf_lo(unsigned u) { return __uint_as_float(u << 16); }
__device__ __forceinline__ float bf_hi(unsigned u) { return __uint_as_float(u & 0xffff0000u); }
__device__ __forceinline__ ull agld(const ull* p) {
    return __hip_atomic_load(p, __ATOMIC_RELAXED, __HIP_MEMORY_SCOPE_AGENT);
}
__device__ __forceinline__ unsigned pk2(ull v) {
    return (unsigned)f2bf(__uint_as_float((unsigned)v)) |
           ((unsigned)f2bf(__uint_as_float((unsigned)(v >> 32))) << 16);
}

// ---------------- prep kernels ----------------

__global__ __launch_bounds__(256) void k_castpad(const float* __restrict__ in,
        ushort* __restrict__ out, int R, int Rpad, int K, int ldi, int off) {
    size_t i = ((size_t)blockIdx.x * 256 + threadIdx.x) * 8;
    if (i >= (size_t)Rpad * K) return;
    int r = (int)(i / K), k = (int)(i % K);
    uint4 o = {0, 0, 0, 0};
    if (r < R) {
        const float* p = in + (size_t)r * ldi + off + k;
        float4 a = *(const float4*)(p);
        float4 b = *(const float4*)(p + 4);
        o.x = (unsigned)f2bf(a.x) | ((unsigned)f2bf(a.y) << 16);
        o.y = (unsigned)f2bf(a.z) | ((unsigned)f2bf(a.w) << 16);
        o.z = (unsigned)f2bf(b.x) | ((unsigned)f2bf(b.y) << 16);
        o.w = (unsigned)f2bf(b.z) | ((unsigned)f2bf(b.w) << 16);
    }
    *(uint4*)(out + i) = o;
}

// gather token embeddings: embG[(t*32+b)][k] = bf16(embed[tok]*(tok!=0))
__global__ __launch_bounds__(128) void k_embg(const int* __restrict__ toks,
        const float* __restrict__ embed, ushort* __restrict__ embG) {
    int row = blockIdx.x;
    int t = row >> 5, b = row & 31;
    int tok = toks[b * 64 + t];
    int e = threadIdx.x * 4;
    uint2 o = {0, 0};
    if (tok != 0) {
        float4 a = *(const float4*)&embed[(size_t)tok * 512 + e];
        o.x = (unsigned)f2bf(a.x) | ((unsigned)f2bf(a.y) << 16);
        o.y = (unsigned)f2bf(a.z) | ((unsigned)f2bf(a.w) << 16);
    }
    *(uint2*)&embG[(size_t)row * 512 + e] = o;
}

// C[m][n] = sum_k A[m][k]*B[n][k]
__global__ __launch_bounds__(256) void k_gemm(const ushort* __restrict__ A,
        const ushort* __restrict__ B, float* __restrict__ C, int N, int K) {
    __shared__ ushort Al[128][72];
    __shared__ ushort Bl[128][72];
    int n0 = blockIdx.x * 128, m0 = blockIdx.y * 128;
    int tid = threadIdx.x, lane = tid & 63, wid = tid >> 6;
    int wm = wid >> 1, wn = wid & 1;
    v4f acc[4][4] = {};
    for (int kt = 0; kt < K; kt += 64) {
        __syncthreads();
        #pragma unroll
        for (int i = 0; i < 4; i++) {
            int idx = i * 256 + tid;
            int row = idx >> 3, c8 = (idx & 7) * 8;
            *(uint4*)&Al[row][c8] = *(const uint4*)&A[(size_t)(m0 + row) * K + kt + c8];
            *(uint4*)&Bl[row][c8] = *(const uint4*)&B[(size_t)(n0 + row) * K + kt + c8];
        }
        __syncthreads();
        #pragma unroll
        for (int kk = 0; kk < 2; kk++) {
            v8s a[4], bfr[4];
            int ko = kk * 32 + (lane >> 4) * 8;
            #pragma unroll
            for (int mi = 0; mi < 4; mi++)
                a[mi] = *(const v8s*)&Al[wm * 64 + mi * 16 + (lane & 15)][ko];
            #pragma unroll
            for (int ni = 0; ni < 4; ni++)
                bfr[ni] = *(const v8s*)&Bl[wn * 64 + ni * 16 + (lane & 15)][ko];
            #pragma unroll
            for (int mi = 0; mi < 4; mi++)
                #pragma unroll
                for (int ni = 0; ni < 4; ni++)
                    acc[mi][ni] = __builtin_amdgcn_mfma_f32_16x16x32_bf16(a[mi], bfr[ni], acc[mi][ni], 0, 0, 0);
        }
    }
    int col = lane & 15, rbase = (lane >> 4) * 4;
    #pragma unroll
    for (int mi = 0; mi < 4; mi++)
        #pragma unroll
        for (int ni = 0; ni < 4; ni++)
            #pragma unroll
            for (int r = 0; r < 4; r++) {
                int m = m0 + wm * 64 + mi * 16 + rbase + r;
                int v = n0 + wn * 64 + ni * 16 + col;
                C[(size_t)m * N + v] = acc[mi][ni][r];
            }
}

__global__ __launch_bounds__(256) void k_gmean(const float* __restrict__ img,
                                               float* __restrict__ g) {
    int b = blockIdx.x;
    for (int d = threadIdx.x; d < 2048; d += 256) {
        float s = 0.f;
        for (int ss = 0; ss < 49; ss++) s += img[((size_t)(b * 49 + ss)) * 2048 + d];
        g[b * 2048 + d] = s * (1.f / 49.f);
    }
}

__global__ __launch_bounds__(256) void k_h0c0(const float* __restrict__ g,
        const float* __restrict__ Wh0, const float* __restrict__ bh0,
        const float* __restrict__ Wc0, const float* __restrict__ bc0,
        float* __restrict__ h0, float* __restrict__ c0) {
    int b = blockIdx.x >> 1, m = blockIdx.x & 1;
    __shared__ float gs[2048];
    for (int d = threadIdx.x; d < 2048; d += 256) gs[d] = g[b * 2048 + d];
    __syncthreads();
    const float* W = m ? Wc0 : Wh0;
    const float* bb = m ? bc0 : bh0;
    float* out = m ? c0 : h0;
    for (int r = threadIdx.x; r < 512; r += 256) {
        float acc = 0.f;
        const float* wr = W + (size_t)r * 2048;
        for (int d = 0; d < 2048; d += 4) {
            float4 w = *(const float4*)(wr + d);
            acc += w.x * gs[d] + w.y * gs[d + 1] + w.z * gs[d + 2] + w.w * gs[d + 3];
        }
        out[b * 512 + r] = ftanh(acc + bb[r]) * 0.5f;
    }
}

// ---------------- persistent recurrence ----------------
// 128 gates blocks (jc x bg): LDS-pinned weight slice, MFMA gates GEMM.
// 32 attn blocks: per-batch attention + LN.
// Sync via per-producer epoch flags (64B-padded slots), no global barrier.
// __syncthreads before a flag store drains vmcnt for all waves, so an
// observed flag implies that block's agent-scope stores are LLC-visible.
// H double-buffered by step parity (WAR); XN single-buffer (safe: attn
// writes XN(t+1) only after all XN(t) consumers set their gates flags).

__device__ __forceinline__ void waitflags(unsigned* FLG, int base, int stride,
                                          int n, unsigned tgt) {
    if (threadIdx.x < 64) {
        bool done;
        do {
            unsigned v = tgt;
            if ((int)threadIdx.x < n)
                v = __hip_atomic_load(FLG + (base + (int)threadIdx.x * stride) * 16,
                                      __ATOMIC_RELAXED, __HIP_MEMORY_SCOPE_AGENT);
            done = __all((int)(v >= tgt));
            if (!done) __builtin_amdgcn_s_sleep(1);
        } while (!done);
    }
    __syncthreads();
}

union SMem {
    struct {                       // gates role (blocks 0..127)
        ushort wh[64][520];        // W_hh rows (64 = 4 gates x 16 j), bf16
        ushort wi[64][520];        // W_ih rows
        ushort hsb[16][520];       // h / xn staged bf16 (rows 8..15 zero)
        float gtmp[4][16][16];     // [gate][jl][m]
    } g;                           // 153856 B
    struct {                       // attention role (blocks 128..159)
        float hb[512];
        float ebs[512];
        float php[8][128];
        float ph[128];
        float scp[64][16];
        float wsm[64];
        float xps[2][512];
        float wred[8][2];
        float bc[2];
    } a;
};

__global__ __launch_bounds__(1024, 1) void k_persist(
        const int* __restrict__ toks, const float* __restrict__ embed,
        const float* __restrict__ lng, const float* __restrict__ lnb,
        const float* __restrict__ bih, const float* __restrict__ bhh,
        const float* __restrict__ wsc, const ushort* __restrict__ whidbf,
        const ushort* __restrict__ whhbf, const ushort* __restrict__ wihbf,
        const float* __restrict__ proj, const float* __restrict__ imgEM,
        const float* __restrict__ embM, float* __restrict__ H,
        const float* __restrict__ C0, float* __restrict__ XN,
        unsigned* __restrict__ FLG, ushort* __restrict__ h2bf) {
    __shared__ SMem sm;
    int blk = blockIdx.x, tid = threadIdx.x;

    if (blk < 128) {
        // ---------------- gates role ----------------
        int jc = blk >> 2, bg = blk & 3, b0 = bg * 8;
        int wid = tid >> 6, lane = tid & 63;
        int gate = wid & 3;
        // pin weight slice (once): rows r = gate*16+jl -> R = gate*512 + jc*16 + jl
        for (int i = tid; i < 4096; i += 1024) {
            int rr = i >> 6, c8 = (i & 63) * 8;
            size_t R = (size_t)((rr >> 4) * 512 + jc * 16 + (rr & 15)) * 512 + c8;
            *(uint4*)&sm.g.wh[rr][c8] = *(const uint4*)&whhbf[R];
            *(uint4*)&sm.g.wi[rr][c8] = *(const uint4*)&wihbf[R];
        }
        for (int i = tid; i < 2080; i += 1024) ((ull*)sm.g.hsb)[i] = 0;
        float c_reg = 0.f, bs0 = 0.f, bs1 = 0.f, bs2 = 0.f, bs3 = 0.f;
        if (tid < 128) {
            int jl = tid >> 3, bb = tid & 7;
            int j = jc * 16 + jl;
            c_reg = C0[(b0 + bb) * 512 + j];
            bs0 = bih[j] + bhh[j];
            bs1 = bih[512 + j] + bhh[512 + j];
            bs2 = bih[1024 + j] + bhh[1024 + j];
            bs3 = bih[1536 + j] + bhh[1536 + j];
        }
        __syncthreads();

        for (int t = 0; t < NT; t++) {
            // wait H(t) producers: flags g[jc'*4+bg] >= t
            waitflags(FLG, bg, 4, 32, (unsigned)t);
            {   // stage h -> hsb bf16 (rows 0..7)
                const float* Hb = H + (t & 1) * 16384 + b0 * 512;
                if (tid < 512) {
                    int bb = tid >> 6, c8 = (tid & 63) * 8;
                    const ull* p = (const ull*)(Hb + bb * 512 + c8);
                    uint4 o = { pk2(agld(p)), pk2(agld(p + 1)),
                                pk2(agld(p + 2)), pk2(agld(p + 3)) };
                    *(uint4*)&sm.g.hsb[bb][c8] = o;
                }
            }
            __syncthreads();
            v4f acc = {};
            if (wid < 4) {
                #pragma unroll
                for (int ks = 0; ks < 16; ks++) {
                    int ko = ks * 32 + (lane >> 4) * 8;
                    v8s a = *(const v8s*)&sm.g.hsb[lane & 15][ko];
                    v8s b = *(const v8s*)&sm.g.wh[gate * 16 + (lane & 15)][ko];
                    acc = __builtin_amdgcn_mfma_f32_16x16x32_bf16(a, b, acc, 0, 0, 0);
                }
            }
            // wait XN(t): aflags >= t+1
            waitflags(FLG, 128 + b0, 1, 8, (unsigned)(t + 1));
            {   // stage xn -> hsb bf16
                const float* Xb = XN + b0 * 512;
                if (tid < 512) {
                    int bb = tid >> 6, c8 = (tid & 63) * 8;
                    const ull* p = (const ull*)(Xb + bb * 512 + c8);
                    uint4 o = { pk2(agld(p)), pk2(agld(p + 1)),
                                pk2(agld(p + 2)), pk2(agld(p + 3)) };
                    *(uint4*)&sm.g.hsb[bb][c8] = o;
                }
            }
            __syncthreads();
            if (wid < 4) {
                #pragma unroll
                for (int ks = 0; ks < 16; ks++) {
                    int ko = ks * 32 + (lane >> 4) * 8;
                    v8s a = *(const v8s*)&sm.g.hsb[lane & 15][ko];
                    v8s b = *(const v8s*)&sm.g.wi[gate * 16 + (lane & 15)][ko];
                    acc = __builtin_amdgcn_mfma_f32_16x16x32_bf16(a, b, acc, 0, 0, 0);
                }
                #pragma unroll
                for (int q = 0; q < 4; q++)
                    sm.g.gtmp[gate][lane & 15][(lane >> 4) * 4 + q] = acc[q];
            }
            __syncthreads();
            if (tid < 128) {
                int jl = tid >> 3, bb = tid & 7;
                float vi = sm.g.gtmp[0][jl][bb] + bs0;
                float vf = sm.g.gtmp[1][jl][bb] + bs1;
                float vg = sm.g.gtmp[2][jl][bb] + bs2;
                float vo = sm.g.gtmp[3][jl][bb] + bs3;
                float c2 = fsig(vf) * c_reg + fsig(vi) * ftanh(vg);
                float h2 = fsig(vo) * ftanh(c2);
                c_reg = c2;
                int bglob = b0 + bb, j = jc * 16 + jl;
                __hip_atomic_store((unsigned*)&H[((t + 1) & 1) * 16384 + bglob * 512 + j],
                                   __float_as_uint(h2), __ATOMIC_RELAXED, __HIP_MEMORY_SCOPE_AGENT);
                h2bf[(size_t)(t * 32 + bglob) * 512 + j] = f2bf(h2);
            }
            __syncthreads();
            if (tid == 0)
                __hip_atomic_store(FLG + blk * 16, (unsigned)(t + 1),
                                   __ATOMIC_RELAXED, __HIP_MEMORY_SCOPE_AGENT);
        }
    } else {
        // ---------------- attention role ----------------
        int b = blk - 128, bgb = b >> 3;
        for (int t = 0; t < NT; t++) {
            // wait H(t) producers of this batch-group
            waitflags(FLG, bgb, 4, 32, (unsigned)t);
            int tok = toks[b * 64 + t];
            if (tid < 256) {
                ull v = agld((const ull*)(H + (t & 1) * 16384) + b * 256 + tid);
                *(ull*)&sm.a.hb[tid * 2] = v;
            } else if (tid < 768) {
                int k = tid - 256;
                sm.a.ebs[k] = (tok == 0) ? 0.f : embed[(size_t)tok * 512 + k];
            }
            __syncthreads();
            {   // ph partials (whid from L2, bf16)
                int a = tid & 127, kq = tid >> 7;
                const ushort* wr2 = whidbf + (size_t)a * 512 + kq * 64;
                const float* hp = sm.a.hb + kq * 64;
                float p = 0.f;
                #pragma unroll
                for (int k = 0; k < 64; k += 8) {
                    uint4 q = *(const uint4*)(wr2 + k);
                    float4 ha = *(const float4*)(hp + k);
                    float4 hb4 = *(const float4*)(hp + k + 4);
                    p += bf_lo(q.x)*ha.x + bf_hi(q.x)*ha.y + bf_lo(q.y)*ha.z + bf_hi(q.y)*ha.w
                       + bf_lo(q.z)*hb4.x + bf_hi(q.z)*hb4.y + bf_lo(q.w)*hb4.z + bf_hi(q.w)*hb4.w;
                }
                sm.a.php[kq][a] = p;
            }
            __syncthreads();
            if (tid < 128) {
                float p = 0.f;
                #pragma unroll
                for (int kq = 0; kq < 8; kq++) p += sm.a.php[kq][tid];
                sm.a.ph[tid] = p;
            }
            __syncthreads();
            {   // score partials
                int s = tid >> 4, aq = tid & 15;
                float p = 0.f;
                if (s < 49) {
                    const float* pr = proj + (size_t)(b * 49 + s) * 128 + aq * 8;
                    #pragma unroll
                    for (int a = 0; a < 8; a++)
                        p += ftanh(pr[a] + sm.a.ph[aq * 8 + a]) * wsc[aq * 8 + a];
                }
                sm.a.scp[s][aq] = p;
            }
            __syncthreads();
            if (tid < 64) {
                float v = 0.f;
                #pragma unroll
                for (int q = 0; q < 16; q++) v += sm.a.scp[tid][q];
                if (tid >= 49) v = -1e30f;
                float m = v;
                for (int o = 32; o > 0; o >>= 1) m = fmaxf(m, __shfl_xor(m, o));
                float e = (tid < 49) ? __expf(v - m) : 0.f;
                float su = e;
                for (int o = 32; o > 0; o >>= 1) su += __shfl_xor(su, o);
                sm.a.wsm[tid] = e / su;
            }
            __syncthreads();
            {   // x = embM + sum_s w_s imgEM   (split s over 2 halves)
                int e = tid & 511, sh = tid >> 9;
                float xp = 0.f;
                if (sh == 0) xp = embM[(size_t)(t * 32 + b) * 512 + e];
                int s0 = sh * 25, s1 = sh ? 49 : 25;
                for (int s = s0; s < s1; s++)
                    xp += sm.a.wsm[s] * imgEM[(size_t)(b * 49 + s) * 512 + e];
                sm.a.xps[sh][e] = xp;
            }
            __syncthreads();
            if (tid < 512) {
                float x = fmaxf(sm.a.xps[0][tid] + sm.a.xps[1][tid], 0.f);
                float s = x, s2 = x * x;
                for (int o = 32; o > 0; o >>= 1) { s += __shfl_xor(s, o); s2 += __shfl_xor(s2, o); }
                if ((tid & 63) == 0) { sm.a.wred[tid >> 6][0] = s; sm.a.wred[tid >> 6][1] = s2; }
            }
            __syncthreads();
            if (tid == 0) {
                float s = 0.f, s2 = 0.f;
                #pragma unroll
                for (int w = 0; w < 8; w++) { s += sm.a.wred[w][0]; s2 += sm.a.wred[w][1]; }
                float mu = s * (1.f / 512.f);
                float var = s2 * (1.f / 512.f) - mu * mu;
                sm.a.bc[0] = mu; sm.a.bc[1] = rsqrtf(var + 1e-5f);
            }
            __syncthreads();
            if (tid < 512) {
                float x = fmaxf(sm.a.xps[0][tid] + sm.a.xps[1][tid], 0.f);
                float xn = (x - sm.a.bc[0]) * sm.a.bc[1] * lng[tid] + lnb[tid] + sm.a.ebs[tid];
                __hip_atomic_store((unsigned*)&XN[b * 512 + tid], __float_as_uint(xn),
                                   __ATOMIC_RELAXED, __HIP_MEMORY_SCOPE_AGENT);
            }
            __syncthreads();
            if (tid == 0)
                __hip_atomic_store(FLG + (128 + b) * 16, (unsigned)(t + 1),
                                   __ATOMIC_RELAXED, __HIP_MEMORY_SCOPE_AGENT);
        }
    }
}

// ---------------- deferred head GEMM ----------------
__global__ __launch_bounds__(256) void k_head(const ushort* __restrict__ h2bf,
        const ushort* __restrict__ Wbf, float* __restrict__ out) {
    __shared__ ushort Al[128][72];
    __shared__ ushort Bl[128][72];
    int n0 = blockIdx.x * 128, m0 = blockIdx.y * 128;
    int tid = threadIdx.x, lane = tid & 63, wid = tid >> 6;
    int wm = wid >> 1, wn = wid & 1;
    v4f acc[4][4] = {};
    for (int kt = 0; kt < 512; kt += 64) {
        __syncthreads();
        #pragma unroll
        for (int i = 0; i < 4; i++) {
            int idx = i * 256 + tid;
            int row = idx >> 3, c8 = (idx & 7) * 8;
            *(uint4*)&Al[row][c8] = *(const uint4*)&h2bf[(size_t)(m0 + row) * 512 + kt + c8];
            *(uint4*)&Bl[row][c8] = *(const uint4*)&Wbf[(size_t)(n0 + row) * 512 + kt + c8];
        }
        __syncthreads();
        #pragma unroll
        for (int kk = 0; kk < 2; kk++) {
            v8s a[4], bfr[4];
            int ko = kk * 32 + (lane >> 4) * 8;
            #pragma unroll
            for (int mi = 0; mi < 4; mi++)
                a[mi] = *(const v8s*)&Al[wm * 64 + mi * 16 + (lane & 15)][ko];
            #pragma unroll
            for (int ni = 0; ni < 4; ni++)
                bfr[ni] = *(const v8s*)&Bl[wn * 64 + ni * 16 + (lane & 15)][ko];
            #pragma unroll
            for (int mi = 0; mi < 4; mi++)
                #pragma unroll
                for (int ni = 0; ni < 4; ni++)
                    acc[mi][ni] = __builtin_amdgcn_mfma_f32_16x16x32_bf16(a[mi], bfr[ni], acc[mi][ni], 0, 0, 0);
        }
    }
    int col = lane & 15, rbase = (lane >> 4) * 4;
    #pragma unroll
    for (int mi = 0; mi < 4; mi++)
        #pragma unroll
        for (int ni = 0; ni < 4; ni++)
            #pragma unroll
            for (int r = 0; r < 4; r++) {
                int m = m0 + wm * 64 + mi * 16 + rbase + r;
                int v = n0 + wn * 64 + ni * 16 + col;
                int b = m & 31, t = m >> 5;
                out[((size_t)(b * 64 + t)) * 32000 + v] = acc[mi][ni][r];
            }
}

// ---------------- launch ----------------
extern "C" void kernel_launch(void* const* d_in, const int* in_sizes, int n_in,
                              void* d_out, int out_size, void* d_ws, size_t ws_size,
                              hipStream_t stream) {
    const float* img    = (const float*)d_in[0];
    const int*   toks   = (const int*)d_in[1];
    const float* embed  = (const float*)d_in[2];
    const float* W_ctx  = (const float*)d_in[3];
    const float* W_mix  = (const float*)d_in[4];
    const float* ln_g   = (const float*)d_in[5];
    const float* ln_b   = (const float*)d_in[6];
    const float* W_ih   = (const float*)d_in[7];
    const float* W_hh   = (const float*)d_in[8];
    const float* b_ih   = (const float*)d_in[9];
    const float* b_hh   = (const float*)d_in[10];
    const float* W_head = (const float*)d_in[11];
    const float* W_img  = (const float*)d_in[12];
    const float* W_hid  = (const float*)d_in[13];
    const float* w_sc   = (const float*)d_in[14];
    const float* W_h0   = (const float*)d_in[15];
    const float* b_h0   = (const float*)d_in[16];
    const float* W_c0   = (const float*)d_in[17];
    const float* b_c0   = (const float*)d_in[18];

    float* out = (float*)d_out;
    float* ws  = (float*)d_ws;
    ushort* Wbf    = (ushort*)(ws + WS_WBF);
    ushort* h2bf   = (ushort*)(ws + WS_H2BF);
    float*  imgEM  = ws + WS_IMGEM;
    float*  proj   = ws + WS_PROJ;
    float*  embM   = ws + WS_EMBM;
    ushort* whhbf  = (ushort*)(ws + WS_WHHBF);
    ushort* wihbf  = (ushort*)(ws + WS_WIHBF);
    ushort* whidbf = (ushort*)(ws + WS_WHIDBF);
    float*  H      = ws + WS_H;
    float*  XN     = ws + WS_XN;
    float*  C      = ws + WS_C;
    unsigned* flg  = (unsigned*)(ws + WS_FLAGS);
    float*  g      = ws + WS_G;
    // prep scratch (inside Wbf slot)
    ushort* imgbf   = (ushort*)(ws + PS_IMGBF);
    ushort* wctxbf  = (ushort*)(ws + PS_WCTXBF);
    ushort* wimgbf  = (ushort*)(ws + PS_WIMGBF);
    ushort* wmixRbf = (ushort*)(ws + PS_WMIXRBF);
    float*  imgE    = ws + PS_IMGE;
    ushort* imgEbf  = (ushort*)(ws + PS_IMGEBF);
    ushort* embG    = (ushort*)(ws + PS_EMBG);
    ushort* wmixLbf = (ushort*)(ws + PS_WMIXLBF);

    // prep A: casts into scratch
    k_castpad<<<1664, 256, 0, stream>>>(img,   imgbf,   1568, 1664, 2048, 2048, 0);
    k_castpad<<<512,  256, 0, stream>>>(W_ctx, wctxbf,  512,  512,  2048, 2048, 0);
    k_castpad<<<128,  256, 0, stream>>>(W_img, wimgbf,  128,  128,  2048, 2048, 0);
    k_castpad<<<128,  256, 0, stream>>>(W_mix, wmixRbf, 512,  512,  512,  1024, 512);
    k_castpad<<<128,  256, 0, stream>>>(W_mix, wmixLbf, 512,  512,  512,  1024, 0);
    k_embg<<<2048, 128, 0, stream>>>(toks, embed, embG);
    // prep B: MFMA GEMMs
    k_gemm<<<dim3(4, 13), 256, 0, stream>>>(imgbf, wctxbf, imgE, 512, 2048);
    k_gemm<<<dim3(1, 13), 256, 0, stream>>>(imgbf, wimgbf, proj, 128, 2048);
    k_gemm<<<dim3(4, 16), 256, 0, stream>>>(embG, wmixLbf, embM, 512, 512);
    k_castpad<<<416, 256, 0, stream>>>(imgE, imgEbf, 1664, 1664, 512, 512, 0);
    k_gemm<<<dim3(4, 13), 256, 0, stream>>>(imgEbf, wmixRbf, imgEM, 512, 512);
    // prep C: persistent bf16 weights
    k_castpad<<<512, 256, 0, stream>>>(W_hh,  whhbf,  2048, 2048, 512, 512, 0);
    k_castpad<<<512, 256, 0, stream>>>(W_ih,  wihbf,  2048, 2048, 512, 512, 0);
    k_castpad<<<32,  256, 0, stream>>>(W_hid, whidbf, 128,  128,  512, 512, 0);
    // prep D: head weights (overwrites scratch region)
    k_castpad<<<8000, 256, 0, stream>>>(W_head, Wbf, 32000, 32000, 512, 512, 0);
    // prep E: init state (h0 into H parity-0 buffer)
    k_gmean<<<32, 256, 0, stream>>>(img, g);
    k_h0c0<<<64, 256, 0, stream>>>(g, W_h0, b_h0, W_c0, b_c0, H, C);
    hipMemsetAsync(flg, 0, 10240, stream);   // 160 flag slots (64B each)

    // recurrence: flag-synced, MFMA gates, LDS-pinned weights
    k_persist<<<NBLK, 1024, 0, stream>>>(toks, embed, ln_g, ln_b, b_ih, b_hh, w_sc,
                                         whidbf, whhbf, wihbf, proj, imgEM, embM,
                                         H, C, XN, flg, h2bf);

    // deferred batched head GEMM
    k_head<<<dim3(250, 16), 256, 0, stream>>>(h2bf, Wbf, out);
}